// Round 1
// baseline (1110.932 us; speedup 1.0000x reference)
//
#include <hip/hip_runtime.h>
#include <stdint.h>

#define DEV static __device__ __forceinline__

typedef __attribute__((ext_vector_type(8))) short s16x8;
typedef __attribute__((ext_vector_type(4))) float f32x4;

constexpr int BB = 2, LL = 2048, DD = 2048, NH = 16, NKV = 4, HD = 128;
constexpr int Mrows = BB * LL; // 4096

DEV ushort f2bf(float f){
  union { float f; uint32_t u; } v; v.f = f;
  uint32_t u = v.u;
  u += 0x7fffu + ((u >> 16) & 1u);
  return (ushort)(u >> 16);
}
DEV float bf2f(ushort h){
  union { uint32_t u; float f; } v; v.u = ((uint32_t)h) << 16;
  return v.f;
}

// ---------------- fp32 -> bf16 conversion (vectorized) ----------------
__global__ void cvt_kernel(const float* __restrict__ in, ushort* __restrict__ out, int n4){
  int stride = gridDim.x * blockDim.x;
  for (int i = blockIdx.x * blockDim.x + threadIdx.x; i < n4; i += stride){
    float4 v = reinterpret_cast<const float4*>(in)[i];
    ushort4 o = make_ushort4(f2bf(v.x), f2bf(v.y), f2bf(v.z), f2bf(v.w));
    reinterpret_cast<ushort4*>(out)[i] = o;
  }
}

// ---------------- RoPE tables: cos/sin [L][64] fp32 ----------------
__global__ void rope_table_kernel(float* __restrict__ cosT, float* __restrict__ sinT){
  int i = blockIdx.x * blockDim.x + threadIdx.x;
  if (i >= LL * 64) return;
  int l = i >> 6, f = i & 63;
  float inv = __expf(-logf(10000.f) * (float)f / 64.f); // 10000^(-f/64)
  float ang = (float)l * inv;
  float s, c;
  sincosf(ang, &s, &c);   // accurate version: ang up to ~2047 rad
  cosT[i] = c; sinT[i] = s;
}

// ---------------- RoPE apply in place on (B, nh, L, 128) bf16 ----------------
// idx enumerates 8-element chunks; scale folds 1/sqrt(128) for Q.
__global__ void rope_apply_kernel(ushort* __restrict__ t, const float* __restrict__ cosT,
                                  const float* __restrict__ sinT, int total, float scale){
  int idx = blockIdx.x * blockDim.x + threadIdx.x;
  if (idx >= total) return;
  int c = idx & 15;                // chunk within a 128-dim row (d0 = c*8)
  int l = (idx >> 4) & (LL - 1);   // sequence position
  s16x8 v = *reinterpret_cast<const s16x8*>(t + (size_t)idx * 8);
  int fb = (l << 6) + c * 4;       // freq table base (d/2)
  s16x8 o;
  #pragma unroll
  for (int j = 0; j < 4; ++j){
    float x1 = bf2f((ushort)v[2*j]);
    float x2 = bf2f((ushort)v[2*j+1]);
    float co = cosT[fb + j], si = sinT[fb + j];
    o[2*j]   = (short)f2bf((x1 * co - x2 * si) * scale);
    o[2*j+1] = (short)f2bf((x1 * si + x2 * co) * scale);
  }
  *reinterpret_cast<s16x8*>(t + (size_t)idx * 8) = o;
}

// ---------------- async global->LDS helper ----------------
DEV void g2l16(const void* g, void* l){
  __builtin_amdgcn_global_load_lds((__attribute__((address_space(1))) void*)(void*)g,
                                   (__attribute__((address_space(3))) void*)l, 16, 0, 0);
}

// ---------------- bf16 GEMM: C = A(M x Kd) * W(N x Kd)^T ----------------
// MODE 0: write fp32 row-major [row][col] (out projection)
// MODE 1: write bf16 scattered to (B, nheads, L, 128) (QKV projections)
template<int MODE>
__global__ __launch_bounds__(256) void gemm_bt_kernel(const ushort* __restrict__ A,
    const ushort* __restrict__ W, void* __restrict__ outp, int N, int Kd, int nheads)
{
  __shared__ ushort Asm[128 * 32];
  __shared__ ushort Bsm[128 * 32];
  const int tid = threadIdx.x;
  const int lane = tid & 63;
  const int wr = tid >> 7;          // wave row (0..1)
  const int wc = (tid >> 6) & 1;    // wave col (0..1)
  const int lr = lane & 15, lg = lane >> 4;
  const int brow = blockIdx.y * 128, bcol = blockIdx.x * 128;

  f32x4 acc[4][4] = {};

  for (int kb = 0; kb < Kd; kb += 32){
    #pragma unroll
    for (int it = 0; it < 2; ++it){
      int seg = it * 256 + tid;
      int row = seg >> 2, sc = seg & 3;
      g2l16(A + (size_t)(brow + row) * Kd + kb + sc * 8, &Asm[seg * 8]);
    }
    #pragma unroll
    for (int it = 0; it < 2; ++it){
      int seg = it * 256 + tid;
      int row = seg >> 2, sc = seg & 3;
      g2l16(W + (size_t)(bcol + row) * Kd + kb + sc * 8, &Bsm[seg * 8]);
    }
    __syncthreads();
    s16x8 af[4], bfr[4];
    #pragma unroll
    for (int m = 0; m < 4; ++m)
      af[m] = *reinterpret_cast<const s16x8*>(&Asm[(wr*64 + m*16 + lr)*32 + lg*8]);
    #pragma unroll
    for (int n = 0; n < 4; ++n)
      bfr[n] = *reinterpret_cast<const s16x8*>(&Bsm[(wc*64 + n*16 + lr)*32 + lg*8]);
    #pragma unroll
    for (int m = 0; m < 4; ++m)
      #pragma unroll
      for (int n = 0; n < 4; ++n)
        acc[m][n] = __builtin_amdgcn_mfma_f32_16x16x32_bf16(af[m], bfr[n], acc[m][n], 0, 0, 0);
    __syncthreads();
  }

  #pragma unroll
  for (int m = 0; m < 4; ++m)
    #pragma unroll
    for (int n = 0; n < 4; ++n)
      #pragma unroll
      for (int r = 0; r < 4; ++r){
        int row = brow + wr*64 + m*16 + lg*4 + r;
        int col = bcol + wc*64 + n*16 + lr;
        float v = acc[m][n][r];
        if (MODE == 0){
          ((float*)outp)[(size_t)row * N + col] = v;
        } else {
          int b = row >> 11, l = row & (LL - 1);
          int h = col >> 7, d = col & (HD - 1);
          ((ushort*)outp)[(((size_t)(b * nheads + h)) * LL + l) * HD + d] = f2bf(v);
        }
      }
}

// ---------------- flash attention: 1 wave per (b, h, 16 q-rows) ----------------
// Q: (B, NH, L, 128) bf16 (already RoPE'd and pre-scaled by 1/sqrt(128))
// K: (B, NKV, L, 128) bf16 (RoPE'd), V: (B, NKV, L, 128) bf16
// O: (B, L, D) bf16
__global__ __launch_bounds__(64) void attn_kernel(const ushort* __restrict__ Q,
    const ushort* __restrict__ Kt, const ushort* __restrict__ V, ushort* __restrict__ O)
{
  __shared__ ushort pSm[16 * 32];
  __shared__ ushort vT[128 * 40];   // padded stride 40 elems = 80B (16B-aligned, conflict-light)
  const int lane = threadIdx.x;
  const int lr = lane & 15, lg = lane >> 4;
  const int qb = blockIdx.x, bh = blockIdx.y;
  const int b = bh >> 4, h = bh & 15;
  const int kvh = h >> 2;
  const size_t qoff = (size_t)bh * LL * HD;
  const size_t koff = (size_t)(b * NKV + kvh) * LL * HD;
  const int qbase = qb * 16;
  const int qlast = qbase + 15;

  // Q fragments (A-frag): row = lr, k = lg*8 + j, for 4 k-steps
  s16x8 qf[4];
  #pragma unroll
  for (int kk = 0; kk < 4; ++kk)
    qf[kk] = *reinterpret_cast<const s16x8*>(&Q[qoff + (size_t)(qbase + lr) * HD + kk*32 + lg*8]);

  f32x4 of[8] = {};
  float mrun[4], lrun[4];
  #pragma unroll
  for (int r = 0; r < 4; ++r){ mrun[r] = -1e30f; lrun[r] = 0.f; }

  for (int jb = 0; jb <= qlast; jb += 32){
    // ---- S = Q K^T (two 16-col fragments) ----
    f32x4 s0 = {}, s1 = {};
    #pragma unroll
    for (int kk = 0; kk < 4; ++kk){
      s16x8 k0 = *reinterpret_cast<const s16x8*>(&Kt[koff + (size_t)(jb      + lr) * HD + kk*32 + lg*8]);
      s16x8 k1 = *reinterpret_cast<const s16x8*>(&Kt[koff + (size_t)(jb + 16 + lr) * HD + kk*32 + lg*8]);
      s0 = __builtin_amdgcn_mfma_f32_16x16x32_bf16(qf[kk], k0, s0, 0, 0, 0);
      s1 = __builtin_amdgcn_mfma_f32_16x16x32_bf16(qf[kk], k1, s1, 0, 0, 0);
    }
    // ---- causal mask + row max ----
    float mx[4];
    #pragma unroll
    for (int r = 0; r < 4; ++r){
      int row = qbase + lg*4 + r;
      if (jb      + lr > row) s0[r] = -1e30f;
      if (jb + 16 + lr > row) s1[r] = -1e30f;
      mx[r] = fmaxf(s0[r], s1[r]);
    }
    #pragma unroll
    for (int d = 1; d < 16; d <<= 1){
      #pragma unroll
      for (int r = 0; r < 4; ++r) mx[r] = fmaxf(mx[r], __shfl_xor(mx[r], d, 64));
    }
    // ---- online softmax update ----
    float fac[4], psum[4];
    #pragma unroll
    for (int r = 0; r < 4; ++r){
      float mnew = fmaxf(mrun[r], mx[r]);
      fac[r] = __expf(mrun[r] - mnew);
      mrun[r] = mnew;
      s0[r] = __expf(s0[r] - mnew);
      s1[r] = __expf(s1[r] - mnew);
      psum[r] = s0[r] + s1[r];
    }
    #pragma unroll
    for (int d = 1; d < 16; d <<= 1){
      #pragma unroll
      for (int r = 0; r < 4; ++r) psum[r] += __shfl_xor(psum[r], d, 64);
    }
    #pragma unroll
    for (int r = 0; r < 4; ++r) lrun[r] = lrun[r] * fac[r] + psum[r];
    #pragma unroll
    for (int f = 0; f < 8; ++f)
      #pragma unroll
      for (int r = 0; r < 4; ++r) of[f][r] *= fac[r];

    // ---- P (bf16) to LDS in A-frag layout ----
    #pragma unroll
    for (int r = 0; r < 4; ++r){
      pSm[(lg*4 + r) * 32 + lr]      = f2bf(s0[r]);
      pSm[(lg*4 + r) * 32 + 16 + lr] = f2bf(s1[r]);
    }
    // ---- stage V block transposed: vT[d][kv], padded stride 40 ----
    #pragma unroll
    for (int it = 0; it < 8; ++it){
      int seg = it * 64 + lane;       // 512 segments of 8 elems
      int row = seg >> 4;             // kv row 0..31
      int dc = (seg & 15) * 8;        // d col
      s16x8 vv = *reinterpret_cast<const s16x8*>(&V[koff + (size_t)(jb + row) * HD + dc]);
      #pragma unroll
      for (int j = 0; j < 8; ++j) vT[(dc + j) * 40 + row] = (ushort)vv[j];
    }
    __syncthreads();
    // ---- O += P * V ----
    s16x8 pa = *reinterpret_cast<const s16x8*>(&pSm[lr * 32 + lg * 8]);
    #pragma unroll
    for (int f = 0; f < 8; ++f){
      s16x8 vb = *reinterpret_cast<const s16x8*>(&vT[(f*16 + lr) * 40 + lg * 8]);
      of[f] = __builtin_amdgcn_mfma_f32_16x16x32_bf16(pa, vb, of[f], 0, 0, 0);
    }
    __syncthreads();
  }

  // ---- epilogue: O/l to (B, L, D) bf16 ----
  #pragma unroll
  for (int f = 0; f < 8; ++f)
    #pragma unroll
    for (int r = 0; r < 4; ++r){
      int row = qbase + lg*4 + r;
      int col = h * HD + f*16 + lr;
      O[((size_t)b * LL + row) * DD + col] = f2bf(of[f][r] / lrun[r]);
    }
}

// ---------------- launcher ----------------
extern "C" void kernel_launch(void* const* d_in, const int* in_sizes, int n_in,
                              void* d_out, int out_size, void* d_ws, size_t ws_size,
                              hipStream_t stream)
{
  const float* x  = (const float*)d_in[0];
  const float* wq = (const float*)d_in[1];
  const float* wk = (const float*)d_in[2];
  const float* wv = (const float*)d_in[3];
  const float* wo = (const float*)d_in[4];
  float* out = (float*)d_out;

  char* p = (char*)d_ws;
  auto alloc = [&](size_t bytes) -> void* {
    void* r = (void*)p; p += (bytes + 255) & ~(size_t)255; return r;
  };
  ushort* xb   = (ushort*)alloc((size_t)Mrows * DD * 2);        // 16 MB
  ushort* wqb  = (ushort*)alloc((size_t)DD * DD * 2);           // 8 MB
  ushort* wkb  = (ushort*)alloc((size_t)NKV * HD * DD * 2);     // 2 MB
  ushort* wvb  = (ushort*)alloc((size_t)NKV * HD * DD * 2);     // 2 MB
  ushort* wob  = (ushort*)alloc((size_t)DD * DD * 2);           // 8 MB
  ushort* qws  = (ushort*)alloc((size_t)BB * NH * LL * HD * 2); // 16 MB
  ushort* kws  = (ushort*)alloc((size_t)BB * NKV * LL * HD * 2);// 4 MB
  ushort* vws  = (ushort*)alloc((size_t)BB * NKV * LL * HD * 2);// 4 MB
  ushort* aows = (ushort*)alloc((size_t)Mrows * DD * 2);        // 16 MB
  float*  cosT = (float*)alloc((size_t)LL * 64 * 4);
  float*  sinT = (float*)alloc((size_t)LL * 64 * 4);

  auto cvt = [&](const float* in, ushort* o, size_t n){
    int n4 = (int)(n / 4);
    int blocks = (n4 + 255) / 256; if (blocks > 2048) blocks = 2048;
    hipLaunchKernelGGL(cvt_kernel, dim3(blocks), dim3(256), 0, stream, in, o, n4);
  };
  cvt(x,  xb,  (size_t)Mrows * DD);
  cvt(wq, wqb, (size_t)DD * DD);
  cvt(wk, wkb, (size_t)NKV * HD * DD);
  cvt(wv, wvb, (size_t)NKV * HD * DD);
  cvt(wo, wob, (size_t)DD * DD);

  hipLaunchKernelGGL(rope_table_kernel, dim3((LL*64)/256), dim3(256), 0, stream, cosT, sinT);

  // QKV projections
  hipLaunchKernelGGL((gemm_bt_kernel<1>), dim3(DD/128, Mrows/128), dim3(256), 0, stream,
                     xb, wqb, (void*)qws, DD, DD, NH);
  hipLaunchKernelGGL((gemm_bt_kernel<1>), dim3((NKV*HD)/128, Mrows/128), dim3(256), 0, stream,
                     xb, wkb, (void*)kws, NKV*HD, DD, NKV);
  hipLaunchKernelGGL((gemm_bt_kernel<1>), dim3((NKV*HD)/128, Mrows/128), dim3(256), 0, stream,
                     xb, wvb, (void*)vws, NKV*HD, DD, NKV);

  // RoPE (Q pre-scaled by 1/sqrt(128))
  {
    int totq = BB * NH * LL * 16;
    hipLaunchKernelGGL(rope_apply_kernel, dim3(totq/256), dim3(256), 0, stream,
                       qws, cosT, sinT, totq, 0.08838834764831845f);
    int totk = BB * NKV * LL * 16;
    hipLaunchKernelGGL(rope_apply_kernel, dim3(totk/256), dim3(256), 0, stream,
                       kws, cosT, sinT, totk, 1.0f);
  }

  // attention
  hipLaunchKernelGGL(attn_kernel, dim3(LL/16, BB*NH), dim3(64), 0, stream,
                     qws, kws, vws, aows);

  // output projection -> fp32
  hipLaunchKernelGGL((gemm_bt_kernel<0>), dim3(DD/128, Mrows/128), dim3(256), 0, stream,
                     aows, wob, (void*)out, DD, DD, 0);
}

// Round 2
// 558.356 us; speedup vs baseline: 1.9896x; 1.9896x over previous
//
#include <hip/hip_runtime.h>
#include <stdint.h>

#define DEV static __device__ __forceinline__

typedef __attribute__((ext_vector_type(8))) short s16x8;
typedef __attribute__((ext_vector_type(4))) float f32x4;

constexpr int BB = 2, LL = 2048, DD = 2048, NH = 16, NKV = 4, HD = 128;
constexpr int Mrows = BB * LL; // 4096

DEV ushort f2bf(float f){
  union { float f; uint32_t u; } v; v.f = f;
  uint32_t u = v.u;
  u += 0x7fffu + ((u >> 16) & 1u);
  return (ushort)(u >> 16);
}
DEV float bf2f(ushort h){
  union { uint32_t u; float f; } v; v.u = ((uint32_t)h) << 16;
  return v.f;
}

// ---------------- fp32 -> bf16 conversion (vectorized) ----------------
__global__ void cvt_kernel(const float* __restrict__ in, ushort* __restrict__ out, int n4){
  int stride = gridDim.x * blockDim.x;
  for (int i = blockIdx.x * blockDim.x + threadIdx.x; i < n4; i += stride){
    float4 v = reinterpret_cast<const float4*>(in)[i];
    ushort4 o = make_ushort4(f2bf(v.x), f2bf(v.y), f2bf(v.z), f2bf(v.w));
    reinterpret_cast<ushort4*>(out)[i] = o;
  }
}

// ---------------- RoPE tables: cos/sin [L][64] fp32 ----------------
__global__ void rope_table_kernel(float* __restrict__ cosT, float* __restrict__ sinT){
  int i = blockIdx.x * blockDim.x + threadIdx.x;
  if (i >= LL * 64) return;
  int l = i >> 6, f = i & 63;
  float inv = __expf(-logf(10000.f) * (float)f / 64.f); // 10000^(-f/64)
  float ang = (float)l * inv;
  float s, c;
  sincosf(ang, &s, &c);
  cosT[i] = c; sinT[i] = s;
}

// ---------------- RoPE apply in place on (B, nh, L, 128) bf16 ----------------
__global__ void rope_apply_kernel(ushort* __restrict__ t, const float* __restrict__ cosT,
                                  const float* __restrict__ sinT, int total, float scale){
  int idx = blockIdx.x * blockDim.x + threadIdx.x;
  if (idx >= total) return;
  int c = idx & 15;                // chunk within a 128-dim row (d0 = c*8)
  int l = (idx >> 4) & (LL - 1);   // sequence position
  s16x8 v = *reinterpret_cast<const s16x8*>(t + (size_t)idx * 8);
  int fb = (l << 6) + c * 4;       // freq table base (d/2)
  s16x8 o;
  #pragma unroll
  for (int j = 0; j < 4; ++j){
    float x1 = bf2f((ushort)v[2*j]);
    float x2 = bf2f((ushort)v[2*j+1]);
    float co = cosT[fb + j], si = sinT[fb + j];
    o[2*j]   = (short)f2bf((x1 * co - x2 * si) * scale);
    o[2*j+1] = (short)f2bf((x1 * si + x2 * co) * scale);
  }
  *reinterpret_cast<s16x8*>(t + (size_t)idx * 8) = o;
}

// ---------------- async global->LDS helper ----------------
DEV void g2l16(const void* g, void* l){
  __builtin_amdgcn_global_load_lds((__attribute__((address_space(1))) void*)(void*)g,
                                   (__attribute__((address_space(3))) void*)l, 16, 0, 0);
}

// ---------------- bf16 GEMM: C = A(M x Kd) * W(N x Kd)^T ----------------
// MODE 0: fp32 row-major [row][col] (out projection)
// MODE 1: bf16 scattered to (B, nheads, L, 128)   (Q, K projections)
// MODE 2: bf16 scattered to (B, nheads, 128, L)   (V projection -> V^T layout)
template<int MODE>
__global__ __launch_bounds__(256) void gemm_bt_kernel(const ushort* __restrict__ A,
    const ushort* __restrict__ W, void* __restrict__ outp, int N, int Kd, int nheads)
{
  __shared__ ushort Asm[128 * 32];
  __shared__ ushort Bsm[128 * 32];
  const int tid = threadIdx.x;
  const int lane = tid & 63;
  const int wr = tid >> 7;          // wave row (0..1)
  const int wc = (tid >> 6) & 1;    // wave col (0..1)
  const int lr = lane & 15, lg = lane >> 4;
  const int brow = blockIdx.y * 128, bcol = blockIdx.x * 128;

  f32x4 acc[4][4] = {};

  for (int kb = 0; kb < Kd; kb += 32){
    #pragma unroll
    for (int it = 0; it < 2; ++it){
      int seg = it * 256 + tid;
      int row = seg >> 2, sc = seg & 3;
      g2l16(A + (size_t)(brow + row) * Kd + kb + sc * 8, &Asm[seg * 8]);
    }
    #pragma unroll
    for (int it = 0; it < 2; ++it){
      int seg = it * 256 + tid;
      int row = seg >> 2, sc = seg & 3;
      g2l16(W + (size_t)(bcol + row) * Kd + kb + sc * 8, &Bsm[seg * 8]);
    }
    __syncthreads();
    s16x8 af[4], bfr[4];
    #pragma unroll
    for (int m = 0; m < 4; ++m)
      af[m] = *reinterpret_cast<const s16x8*>(&Asm[(wr*64 + m*16 + lr)*32 + lg*8]);
    #pragma unroll
    for (int n = 0; n < 4; ++n)
      bfr[n] = *reinterpret_cast<const s16x8*>(&Bsm[(wc*64 + n*16 + lr)*32 + lg*8]);
    #pragma unroll
    for (int m = 0; m < 4; ++m)
      #pragma unroll
      for (int n = 0; n < 4; ++n)
        acc[m][n] = __builtin_amdgcn_mfma_f32_16x16x32_bf16(af[m], bfr[n], acc[m][n], 0, 0, 0);
    __syncthreads();
  }

  #pragma unroll
  for (int m = 0; m < 4; ++m)
    #pragma unroll
    for (int n = 0; n < 4; ++n)
      #pragma unroll
      for (int r = 0; r < 4; ++r){
        int row = brow + wr*64 + m*16 + lg*4 + r;
        int col = bcol + wc*64 + n*16 + lr;
        float v = acc[m][n][r];
        if (MODE == 0){
          ((float*)outp)[(size_t)row * N + col] = v;
        } else {
          int b = row >> 11, l = row & (LL - 1);
          int h = col >> 7, d = col & (HD - 1);
          if (MODE == 1)
            ((ushort*)outp)[(((size_t)(b * nheads + h)) * LL + l) * HD + d] = f2bf(v);
          else
            ((ushort*)outp)[(((size_t)(b * nheads + h)) * HD + d) * LL + l] = f2bf(v);
        }
      }
}

// ---------------- flash attention ----------------
// 4 waves/block, 32 q-rows/wave (128 q rows per block), KV tile = 64.
// Q: (B,NH,L,128) bf16, RoPE'd, pre-scaled by 1/sqrt(128)
// K: (B,NKV,L,128) bf16, RoPE'd
// VT: (B,NKV,128,L) bf16  (V transposed at projection time)
// O: (B,L,D) bf16
// K and VT tiles staged in LDS with XOR chunk-swizzle (chunk ^= row&7), applied
// on BOTH the global source (pre-swizzle, rule #21) and the LDS read.
__global__ __launch_bounds__(256) void attn_kernel(const ushort* __restrict__ Q,
    const ushort* __restrict__ Kg, const ushort* __restrict__ VTg, ushort* __restrict__ O)
{
  __shared__ ushort Ksm[64 * 128];     // 16 KB  [kv][d], swizzled 16B chunks
  __shared__ ushort Vsm[128 * 64];     // 16 KB  [d][kv], swizzled 16B chunks
  __shared__ ushort Psm[4][32 * 72];   // 18 KB  per-wave P tile, pitch 72 (pad)
  const int tid = threadIdx.x;
  const int w = tid >> 6, lane = tid & 63;
  const int lr = lane & 15, lg = lane >> 4;
  const int qbb = (int)gridDim.x - 1 - (int)blockIdx.x;   // heavy blocks first
  const int bh = blockIdx.y;
  const int b = bh >> 4, h = bh & 15, kvh = h >> 2;
  const size_t qoff = (size_t)bh * LL * HD;
  const size_t koff = (size_t)(b * NKV + kvh) * LL * HD;
  const size_t voff = (size_t)(b * NKV + kvh) * HD * LL;
  const int qb0 = qbb * 128;
  const int qrow0 = qb0 + w * 32;
  const int wlast = qrow0 + 31;

  // Q fragments: A-frag rows m*16+lr, k-chunk kk*32+lg*8
  s16x8 qf[2][4];
  #pragma unroll
  for (int m = 0; m < 2; ++m)
    #pragma unroll
    for (int kk = 0; kk < 4; ++kk)
      qf[m][kk] = *reinterpret_cast<const s16x8*>(
          &Q[qoff + (size_t)(qrow0 + m*16 + lr) * HD + kk*32 + lg*8]);

  f32x4 of[2][8] = {};
  float mrun[2][4], lrun[2][4];
  #pragma unroll
  for (int m = 0; m < 2; ++m)
    #pragma unroll
    for (int r = 0; r < 4; ++r){ mrun[m][r] = -1e30f; lrun[m][r] = 0.f; }

  const int ntiles = (qb0 + 128) >> 6;
  for (int t = 0; t < ntiles; ++t){
    const int jb = t << 6;
    // ---- stage K tile (64 rows x 256B = 1024 chunks), source pre-swizzled ----
    #pragma unroll
    for (int it = 0; it < 4; ++it){
      int chunk = it * 256 + tid;
      int r = chunk >> 4, c = chunk & 15;
      g2l16(Kg + koff + (size_t)(jb + r) * HD + ((c ^ (r & 7)) << 3), &Ksm[chunk << 3]);
    }
    // ---- stage VT tile (128 rows x 128B = 1024 chunks) ----
    #pragma unroll
    for (int it = 0; it < 4; ++it){
      int chunk = it * 256 + tid;
      int r = chunk >> 3, c = chunk & 7;
      g2l16(VTg + voff + (size_t)r * LL + jb + ((c ^ (r & 7)) << 3), &Vsm[chunk << 3]);
    }
    __syncthreads();
    if (jb <= wlast){
      // ---- S = Q K^T : 2m x 4n tiles of 16x16 ----
      f32x4 s[2][4] = {};
      #pragma unroll
      for (int kk = 0; kk < 4; ++kk){
        #pragma unroll
        for (int n = 0; n < 4; ++n){
          int row = n*16 + lr;
          s16x8 kf = *reinterpret_cast<const s16x8*>(
              &Ksm[(row << 7) + ((((kk << 2) + lg) ^ (lr & 7)) << 3)]);
          s[0][n] = __builtin_amdgcn_mfma_f32_16x16x32_bf16(qf[0][kk], kf, s[0][n], 0, 0, 0);
          s[1][n] = __builtin_amdgcn_mfma_f32_16x16x32_bf16(qf[1][kk], kf, s[1][n], 0, 0, 0);
        }
      }
      // ---- causal mask (only tiles spanning the diagonal) + row max ----
      const bool needmask = (jb + 63 > qrow0);
      float mx[2][4];
      #pragma unroll
      for (int m = 0; m < 2; ++m)
        #pragma unroll
        for (int r = 0; r < 4; ++r){
          int row = qrow0 + m*16 + lg*4 + r;
          if (needmask){
            #pragma unroll
            for (int n = 0; n < 4; ++n)
              if (jb + n*16 + lr > row) s[m][n][r] = -1e30f;
          }
          float a = fmaxf(s[m][0][r], s[m][1][r]);
          float bb2 = fmaxf(s[m][2][r], s[m][3][r]);
          mx[m][r] = fmaxf(a, bb2);
        }
      #pragma unroll
      for (int d = 1; d < 16; d <<= 1)
        #pragma unroll
        for (int m = 0; m < 2; ++m)
          #pragma unroll
          for (int r = 0; r < 4; ++r)
            mx[m][r] = fmaxf(mx[m][r], __shfl_xor(mx[m][r], d, 64));
      // ---- online softmax ----
      float fac[2][4], psum[2][4];
      #pragma unroll
      for (int m = 0; m < 2; ++m)
        #pragma unroll
        for (int r = 0; r < 4; ++r){
          float mnew = fmaxf(mrun[m][r], mx[m][r]);
          fac[m][r] = __expf(mrun[m][r] - mnew);
          mrun[m][r] = mnew;
          float acc = 0.f;
          #pragma unroll
          for (int n = 0; n < 4; ++n){
            s[m][n][r] = __expf(s[m][n][r] - mnew);
            acc += s[m][n][r];
          }
          psum[m][r] = acc;
        }
      #pragma unroll
      for (int d = 1; d < 16; d <<= 1)
        #pragma unroll
        for (int m = 0; m < 2; ++m)
          #pragma unroll
          for (int r = 0; r < 4; ++r)
            psum[m][r] += __shfl_xor(psum[m][r], d, 64);
      #pragma unroll
      for (int m = 0; m < 2; ++m)
        #pragma unroll
        for (int r = 0; r < 4; ++r)
          lrun[m][r] = lrun[m][r] * fac[m][r] + psum[m][r];
      #pragma unroll
      for (int m = 0; m < 2; ++m)
        #pragma unroll
        for (int f = 0; f < 8; ++f)
          #pragma unroll
          for (int r = 0; r < 4; ++r)
            of[m][f][r] *= fac[m][r];
      // ---- P (bf16) to private LDS tile ----
      #pragma unroll
      for (int m = 0; m < 2; ++m)
        #pragma unroll
        for (int n = 0; n < 4; ++n)
          #pragma unroll
          for (int r = 0; r < 4; ++r)
            Psm[w][(m*16 + lg*4 + r) * 72 + n*16 + lr] = f2bf(s[m][n][r]);
      // ---- O += P * V ----
      s16x8 pa[2][2];
      #pragma unroll
      for (int m = 0; m < 2; ++m)
        #pragma unroll
        for (int ks = 0; ks < 2; ++ks)
          pa[m][ks] = *reinterpret_cast<const s16x8*>(
              &Psm[w][(m*16 + lr) * 72 + ks*32 + lg*8]);
      #pragma unroll
      for (int f = 0; f < 8; ++f)
        #pragma unroll
        for (int ks = 0; ks < 2; ++ks){
          int row = f*16 + lr;
          s16x8 vb = *reinterpret_cast<const s16x8*>(
              &Vsm[(row << 6) + ((((ks << 2) + lg) ^ (lr & 7)) << 3)]);
          #pragma unroll
          for (int m = 0; m < 2; ++m)
            of[m][f] = __builtin_amdgcn_mfma_f32_16x16x32_bf16(pa[m][ks], vb, of[m][f], 0, 0, 0);
        }
    }
    __syncthreads();
  }

  // ---- epilogue ----
  #pragma unroll
  for (int m = 0; m < 2; ++m)
    #pragma unroll
    for (int f = 0; f < 8; ++f)
      #pragma unroll
      for (int r = 0; r < 4; ++r){
        int row = qrow0 + m*16 + lg*4 + r;
        int col = h * HD + f*16 + lr;
        O[((size_t)b * LL + row) * DD + col] = f2bf(of[m][f][r] / lrun[m][r]);
      }
}

// ---------------- launcher ----------------
extern "C" void kernel_launch(void* const* d_in, const int* in_sizes, int n_in,
                              void* d_out, int out_size, void* d_ws, size_t ws_size,
                              hipStream_t stream)
{
  const float* x  = (const float*)d_in[0];
  const float* wq = (const float*)d_in[1];
  const float* wk = (const float*)d_in[2];
  const float* wv = (const float*)d_in[3];
  const float* wo = (const float*)d_in[4];
  float* out = (float*)d_out;

  char* p = (char*)d_ws;
  auto alloc = [&](size_t bytes) -> void* {
    void* r = (void*)p; p += (bytes + 255) & ~(size_t)255; return r;
  };
  ushort* xb   = (ushort*)alloc((size_t)Mrows * DD * 2);
  ushort* wqb  = (ushort*)alloc((size_t)DD * DD * 2);
  ushort* wkb  = (ushort*)alloc((size_t)NKV * HD * DD * 2);
  ushort* wvb  = (ushort*)alloc((size_t)NKV * HD * DD * 2);
  ushort* wob  = (ushort*)alloc((size_t)DD * DD * 2);
  ushort* qws  = (ushort*)alloc((size_t)BB * NH * LL * HD * 2);
  ushort* kws  = (ushort*)alloc((size_t)BB * NKV * LL * HD * 2);
  ushort* vws  = (ushort*)alloc((size_t)BB * NKV * LL * HD * 2);  // V^T layout
  ushort* aows = (ushort*)alloc((size_t)Mrows * DD * 2);
  float*  cosT = (float*)alloc((size_t)LL * 64 * 4);
  float*  sinT = (float*)alloc((size_t)LL * 64 * 4);

  auto cvt = [&](const float* in, ushort* o, size_t n){
    int n4 = (int)(n / 4);
    int blocks = (n4 + 255) / 256; if (blocks > 2048) blocks = 2048;
    hipLaunchKernelGGL(cvt_kernel, dim3(blocks), dim3(256), 0, stream, in, o, n4);
  };
  cvt(x,  xb,  (size_t)Mrows * DD);
  cvt(wq, wqb, (size_t)DD * DD);
  cvt(wk, wkb, (size_t)NKV * HD * DD);
  cvt(wv, wvb, (size_t)NKV * HD * DD);
  cvt(wo, wob, (size_t)DD * DD);

  hipLaunchKernelGGL(rope_table_kernel, dim3((LL*64)/256), dim3(256), 0, stream, cosT, sinT);

  // QKV projections (V written transposed)
  hipLaunchKernelGGL((gemm_bt_kernel<1>), dim3(DD/128, Mrows/128), dim3(256), 0, stream,
                     xb, wqb, (void*)qws, DD, DD, NH);
  hipLaunchKernelGGL((gemm_bt_kernel<1>), dim3((NKV*HD)/128, Mrows/128), dim3(256), 0, stream,
                     xb, wkb, (void*)kws, NKV*HD, DD, NKV);
  hipLaunchKernelGGL((gemm_bt_kernel<2>), dim3((NKV*HD)/128, Mrows/128), dim3(256), 0, stream,
                     xb, wvb, (void*)vws, NKV*HD, DD, NKV);

  // RoPE (Q pre-scaled by 1/sqrt(128))
  {
    int totq = BB * NH * LL * 16;
    hipLaunchKernelGGL(rope_apply_kernel, dim3(totq/256), dim3(256), 0, stream,
                       qws, cosT, sinT, totq, 0.08838834764831845f);
    int totk = BB * NKV * LL * 16;
    hipLaunchKernelGGL(rope_apply_kernel, dim3(totk/256), dim3(256), 0, stream,
                       kws, cosT, sinT, totk, 1.0f);
  }

  // attention: 128 q-rows per block, heavy blocks first
  hipLaunchKernelGGL(attn_kernel, dim3(LL/128, BB*NH), dim3(256), 0, stream,
                     qws, kws, vws, aows);

  // output projection -> fp32
  hipLaunchKernelGGL((gemm_bt_kernel<0>), dim3(DD/128, Mrows/128), dim3(256), 0, stream,
                     aows, wob, (void*)out, DD, DD, 0);
}

// Round 3
// 403.056 us; speedup vs baseline: 2.7563x; 1.3853x over previous
//
#include <hip/hip_runtime.h>
#include <stdint.h>

#define DEV static __device__ __forceinline__

typedef __attribute__((ext_vector_type(8))) short s16x8;
typedef __attribute__((ext_vector_type(4))) short s16x4;
typedef __attribute__((ext_vector_type(4))) float f32x4;

constexpr int BB = 2, LL = 2048, DD = 2048, NH = 16, NKV = 4, HD = 128;
constexpr int Mrows = BB * LL;            // 4096
constexpr int NQKV = DD + 2 * NKV * HD;   // 3072

DEV ushort f2bf(float f){
  union { float f; uint32_t u; } v; v.f = f;
  uint32_t u = v.u;
  u += 0x7fffu + ((u >> 16) & 1u);
  return (ushort)(u >> 16);
}
DEV float bf2f(ushort h){
  union { uint32_t u; float f; } v; v.u = ((uint32_t)h) << 16;
  return v.f;
}

DEV f32x4 mfma32(s16x8 a, s16x8 b, f32x4 c){
  return __builtin_amdgcn_mfma_f32_16x16x32_bf16(a, b, c, 0, 0, 0);
}
DEV f32x4 mfma16(s16x4 a, s16x4 b, f32x4 c){
#if __has_builtin(__builtin_amdgcn_mfma_f32_16x16x16bf16_1k)
  return __builtin_amdgcn_mfma_f32_16x16x16bf16_1k(a, b, c, 0, 0, 0);
#else
  asm volatile("v_mfma_f32_16x16x16_bf16 %0, %1, %2, %0" : "+v"(c) : "v"(a), "v"(b));
  return c;
#endif
}

DEV float vmax4(f32x4 v){ return fmaxf(fmaxf(v[0], v[1]), fmaxf(v[2], v[3])); }
DEV float vsum4(f32x4 v){ return (v[0] + v[1]) + (v[2] + v[3]); }

// ---------------- fused fp32 -> bf16 conversion for all 5 inputs ----------------
__global__ void cvt_all_kernel(const float* __restrict__ x, const float* __restrict__ wq,
                               const float* __restrict__ wk, const float* __restrict__ wv,
                               const float* __restrict__ wo,
                               ushort* __restrict__ xb, ushort* __restrict__ wqkv,
                               ushort* __restrict__ wob){
  constexpr int C0 = Mrows * DD / 4;                 // x
  constexpr int C1 = C0 + DD * DD / 4;               // wq
  constexpr int C2 = C1 + NKV * HD * DD / 4;         // wk
  constexpr int C3 = C2 + NKV * HD * DD / 4;         // wv
  constexpr int C4 = C3 + DD * DD / 4;               // wo
  int stride = gridDim.x * blockDim.x;
  for (int i = blockIdx.x * blockDim.x + threadIdx.x; i < C4; i += stride){
    const float* src; ushort* dst; int j;
    if (i < C0){ src = x;  dst = xb;                              j = i; }
    else if (i < C1){ src = wq; dst = wqkv;                       j = i - C0; }
    else if (i < C2){ src = wk; dst = wqkv + (size_t)DD * DD;     j = i - C1; }
    else if (i < C3){ src = wv; dst = wqkv + (size_t)(DD + NKV*HD) * DD; j = i - C2; }
    else { src = wo; dst = wob;                                   j = i - C3; }
    float4 v = reinterpret_cast<const float4*>(src)[j];
    ushort4 o = make_ushort4(f2bf(v.x), f2bf(v.y), f2bf(v.z), f2bf(v.w));
    reinterpret_cast<ushort4*>(dst)[j] = o;
  }
}

// ---------------- RoPE tables: cos/sin [L][64] fp32 ----------------
__global__ void rope_table_kernel(float* __restrict__ cosT, float* __restrict__ sinT){
  int i = blockIdx.x * blockDim.x + threadIdx.x;
  if (i >= LL * 64) return;
  int l = i >> 6, f = i & 63;
  float inv = __expf(-logf(10000.f) * (float)f / 64.f);
  float ang = (float)l * inv;
  float s, c;
  sincosf(ang, &s, &c);
  cosT[i] = c; sinT[i] = s;
}

// ---------------- fused RoPE apply in place on Q and K ----------------
__global__ void rope_qk_kernel(ushort* __restrict__ q, ushort* __restrict__ k,
                               const float* __restrict__ cosT, const float* __restrict__ sinT){
  constexpr int TQ = BB * NH * LL * 16;
  constexpr int TK = BB * NKV * LL * 16;
  int idx = blockIdx.x * blockDim.x + threadIdx.x;
  if (idx >= TQ + TK) return;
  ushort* t; float scale; int id;
  if (idx < TQ){ t = q; id = idx; scale = 0.08838834764831845f; }  // 1/sqrt(128)
  else { t = k; id = idx - TQ; scale = 1.0f; }
  int c = id & 15;
  int l = (id >> 4) & (LL - 1);
  s16x8 v = *reinterpret_cast<const s16x8*>(t + (size_t)id * 8);
  int fb = (l << 6) + c * 4;
  s16x8 o;
  #pragma unroll
  for (int j = 0; j < 4; ++j){
    float x1 = bf2f((ushort)v[2*j]);
    float x2 = bf2f((ushort)v[2*j+1]);
    float co = cosT[fb + j], si = sinT[fb + j];
    o[2*j]   = (short)f2bf((x1 * co - x2 * si) * scale);
    o[2*j+1] = (short)f2bf((x1 * si + x2 * co) * scale);
  }
  *reinterpret_cast<s16x8*>(t + (size_t)id * 8) = o;
}

// ---------------- async global->LDS helper ----------------
DEV void g2l16(const void* g, void* l){
  __builtin_amdgcn_global_load_lds((__attribute__((address_space(1))) void*)(void*)g,
                                   (__attribute__((address_space(3))) void*)l, 16, 0, 0);
}

// ---------------- fused QKV GEMM: [Q|K|V] = x * Wqkv^T, scatter epilogue ----------------
// Wqkv rows: 0..2047 -> Q (b,h,l,d); 2048..2559 -> K (b,kvh,l,d); 2560..3071 -> V^T (b,kvh,d,l)
__global__ __launch_bounds__(256) void gemm_qkv_kernel(const ushort* __restrict__ A,
    const ushort* __restrict__ W, ushort* __restrict__ qo, ushort* __restrict__ ko,
    ushort* __restrict__ vo)
{
  __shared__ ushort Asm[128 * 32];
  __shared__ ushort Bsm[128 * 32];
  const int tid = threadIdx.x;
  const int lane = tid & 63;
  const int wr = tid >> 7;
  const int wc = (tid >> 6) & 1;
  const int lr = lane & 15, lg = lane >> 4;
  const int brow = blockIdx.y * 128, bcol = blockIdx.x * 128;

  f32x4 acc[4][4] = {};

  for (int kb = 0; kb < DD; kb += 32){
    #pragma unroll
    for (int it = 0; it < 2; ++it){
      int seg = it * 256 + tid;
      int row = seg >> 2, sc = seg & 3;
      g2l16(A + (size_t)(brow + row) * DD + kb + sc * 8, &Asm[seg * 8]);
    }
    #pragma unroll
    for (int it = 0; it < 2; ++it){
      int seg = it * 256 + tid;
      int row = seg >> 2, sc = seg & 3;
      g2l16(W + (size_t)(bcol + row) * DD + kb + sc * 8, &Bsm[seg * 8]);
    }
    __syncthreads();
    s16x8 af[4], bfr[4];
    #pragma unroll
    for (int m = 0; m < 4; ++m)
      af[m] = *reinterpret_cast<const s16x8*>(&Asm[(wr*64 + m*16 + lr)*32 + lg*8]);
    #pragma unroll
    for (int n = 0; n < 4; ++n)
      bfr[n] = *reinterpret_cast<const s16x8*>(&Bsm[(wc*64 + n*16 + lr)*32 + lg*8]);
    #pragma unroll
    for (int m = 0; m < 4; ++m)
      #pragma unroll
      for (int n = 0; n < 4; ++n)
        acc[m][n] = mfma32(af[m], bfr[n], acc[m][n]);
    __syncthreads();
  }

  #pragma unroll
  for (int m = 0; m < 4; ++m)
    #pragma unroll
    for (int n = 0; n < 4; ++n)
      #pragma unroll
      for (int r = 0; r < 4; ++r){
        int row = brow + wr*64 + m*16 + lg*4 + r;
        int col = bcol + wc*64 + n*16 + lr;
        int b = row >> 11, l = row & (LL - 1);
        ushort bv = f2bf(acc[m][n][r]);
        if (col < DD){
          qo[(((size_t)(b * NH + (col >> 7))) * LL + l) * HD + (col & 127)] = bv;
        } else if (col < DD + NKV * HD){
          int c = col - DD;
          ko[(((size_t)(b * NKV + (c >> 7))) * LL + l) * HD + (c & 127)] = bv;
        } else {
          int c = col - DD - NKV * HD;
          vo[(((size_t)(b * NKV + (c >> 7))) * HD + (c & 127)) * LL + l] = bv;
        }
      }
}

// ---------------- output GEMM: out = attn_out * Wo^T (fp32 out) ----------------
__global__ __launch_bounds__(256) void gemm_o_kernel(const ushort* __restrict__ A,
    const ushort* __restrict__ W, float* __restrict__ outp)
{
  __shared__ ushort Asm[128 * 32];
  __shared__ ushort Bsm[128 * 32];
  const int tid = threadIdx.x;
  const int lane = tid & 63;
  const int wr = tid >> 7;
  const int wc = (tid >> 6) & 1;
  const int lr = lane & 15, lg = lane >> 4;
  const int brow = blockIdx.y * 128, bcol = blockIdx.x * 128;

  f32x4 acc[4][4] = {};

  for (int kb = 0; kb < DD; kb += 32){
    #pragma unroll
    for (int it = 0; it < 2; ++it){
      int seg = it * 256 + tid;
      int row = seg >> 2, sc = seg & 3;
      g2l16(A + (size_t)(brow + row) * DD + kb + sc * 8, &Asm[seg * 8]);
    }
    #pragma unroll
    for (int it = 0; it < 2; ++it){
      int seg = it * 256 + tid;
      int row = seg >> 2, sc = seg & 3;
      g2l16(W + (size_t)(bcol + row) * DD + kb + sc * 8, &Bsm[seg * 8]);
    }
    __syncthreads();
    s16x8 af[4], bfr[4];
    #pragma unroll
    for (int m = 0; m < 4; ++m)
      af[m] = *reinterpret_cast<const s16x8*>(&Asm[(wr*64 + m*16 + lr)*32 + lg*8]);
    #pragma unroll
    for (int n = 0; n < 4; ++n)
      bfr[n] = *reinterpret_cast<const s16x8*>(&Bsm[(wc*64 + n*16 + lr)*32 + lg*8]);
    #pragma unroll
    for (int m = 0; m < 4; ++m)
      #pragma unroll
      for (int n = 0; n < 4; ++n)
        acc[m][n] = mfma32(af[m], bfr[n], acc[m][n]);
    __syncthreads();
  }

  #pragma unroll
  for (int m = 0; m < 4; ++m)
    #pragma unroll
    for (int n = 0; n < 4; ++n)
      #pragma unroll
      for (int r = 0; r < 4; ++r){
        int row = brow + wr*64 + m*16 + lg*4 + r;
        int col = bcol + wc*64 + n*16 + lr;
        outp[(size_t)row * DD + col] = acc[m][n][r];
      }
}

// ---------------- flash attention (swapped QK^T, in-register P, dbuf staging) -------
// 4 waves/block, 32 q-rows/wave, KVBLK=64, K/V double-buffered in LDS (XOR swizzle).
// Q: (B,NH,L,128) RoPE'd + pre-scaled; K: (B,NKV,L,128) RoPE'd; VT: (B,NKV,128,L).
// S^T = mfma32(K,Q): lane holds S^T[kv=jb+kt*16+lg*4+r][q=qrow0+qt*16+lr].
// PV: O^T += mfma16(V^T, P^T) — P^T C-layout IS the 16x16x16 B-frag layout (no shuffles).
__global__ __launch_bounds__(256) void attn_kernel(const ushort* __restrict__ Q,
    const ushort* __restrict__ Kg, const ushort* __restrict__ VTg, ushort* __restrict__ O)
{
  __shared__ ushort Ksm[2][64 * 128];   // [kv][d] 16B chunks XOR-swizzled
  __shared__ ushort Vsm[2][128 * 64];   // [d][kv] 16B chunks XOR-swizzled
  const int tid = threadIdx.x;
  const int w = tid >> 6, lane = tid & 63;
  const int lr = lane & 15, lg = lane >> 4;
  const int bh = blockIdx.y;
  const int b = bh >> 4, h = bh & 15, kvh = h >> 2;
  // balanced causal mapping: CU pairs (b=0, b=1) get complementary qbb
  const int qbb = b ? (int)blockIdx.x : ((int)gridDim.x - 1 - (int)blockIdx.x);
  const size_t qoff = (size_t)bh * LL * HD;
  const size_t koff = (size_t)(b * NKV + kvh) * LL * HD;
  const size_t voff = (size_t)(b * NKV + kvh) * HD * LL;
  const int qb0 = qbb * 128;
  const int qrow0 = qb0 + w * 32;
  const int wlast = qrow0 + 31;

  // Q B-frags: lane holds Q[qrow0+qt*16+lr][kk*32+lg*8 ..+7]
  s16x8 qf[2][4];
  #pragma unroll
  for (int qt = 0; qt < 2; ++qt)
    #pragma unroll
    for (int kk = 0; kk < 4; ++kk)
      qf[qt][kk] = *reinterpret_cast<const s16x8*>(
          &Q[qoff + (size_t)(qrow0 + qt*16 + lr) * HD + kk*32 + lg*8]);

  f32x4 of[2][8] = {};
  float mrun[2] = {-1e30f, -1e30f}, lrun[2] = {0.f, 0.f};

  const int nt = 2 * qbb + 2;

  auto STAGE = [&](int buf, int jb){
    #pragma unroll
    for (int it = 0; it < 4; ++it){
      int chunk = it * 256 + tid;
      int r = chunk >> 4, c = chunk & 15;
      g2l16(Kg + koff + (size_t)(jb + r) * HD + ((c ^ (r & 7)) << 3), &Ksm[buf][chunk << 3]);
    }
    #pragma unroll
    for (int it = 0; it < 4; ++it){
      int chunk = it * 256 + tid;
      int r = chunk >> 3, c = chunk & 7;
      g2l16(VTg + voff + (size_t)r * LL + jb + ((c ^ (r & 7)) << 3), &Vsm[buf][chunk << 3]);
    }
  };
  STAGE(0, 0);

  for (int t = 0; t < nt; ++t){
    const int jb = t << 6, cur = t & 1;
    __syncthreads();                       // drains tile-t loads (flew under compute(t-1))
    if (t + 1 < nt) STAGE(cur ^ 1, (t + 1) << 6);
    if (jb <= wlast){
      // ---- S^T = K Q^T ----
      f32x4 s[4][2] = {};
      __builtin_amdgcn_s_setprio(1);
      #pragma unroll
      for (int kk = 0; kk < 4; ++kk)
        #pragma unroll
        for (int kt = 0; kt < 4; ++kt){
          s16x8 kf = *reinterpret_cast<const s16x8*>(
              &Ksm[cur][((kt*16 + lr) << 7) + (((kk*4 + lg) ^ (lr & 7)) << 3)]);
          s[kt][0] = mfma32(kf, qf[0][kk], s[kt][0]);
          s[kt][1] = mfma32(kf, qf[1][kk], s[kt][1]);
        }
      __builtin_amdgcn_s_setprio(0);
      // ---- causal mask (diagonal-spanning tiles only) ----
      if (jb + 63 > qrow0){
        #pragma unroll
        for (int kt = 0; kt < 4; ++kt){
          int kvg = jb + kt*16 + lg*4;
          #pragma unroll
          for (int qt = 0; qt < 2; ++qt){
            int qg = qrow0 + qt*16 + lr;
            #pragma unroll
            for (int r = 0; r < 4; ++r)
              if (kvg + r > qg) s[kt][qt][r] = -1e30f;
          }
        }
      }
      // ---- row max over kv (in-lane 16 + 2 shuffles) ----
      float mx[2];
      #pragma unroll
      for (int qt = 0; qt < 2; ++qt){
        mx[qt] = fmaxf(fmaxf(vmax4(s[0][qt]), vmax4(s[1][qt])),
                       fmaxf(vmax4(s[2][qt]), vmax4(s[3][qt])));
        mx[qt] = fmaxf(mx[qt], __shfl_xor(mx[qt], 16, 64));
        mx[qt] = fmaxf(mx[qt], __shfl_xor(mx[qt], 32, 64));
      }
      // ---- defer-max online softmax (T13, THR=8) ----
      int small = (mx[0] <= mrun[0] + 8.f) && (mx[1] <= mrun[1] + 8.f);
      if (!__all(small)){
        float mn0 = fmaxf(mrun[0], mx[0]), mn1 = fmaxf(mrun[1], mx[1]);
        float fac0 = __expf(mrun[0] - mn0), fac1 = __expf(mrun[1] - mn1);
        mrun[0] = mn0; mrun[1] = mn1;
        lrun[0] *= fac0; lrun[1] *= fac1;
        #pragma unroll
        for (int f = 0; f < 8; ++f){ of[0][f] *= fac0; of[1][f] *= fac1; }
      }
      float ps[2] = {0.f, 0.f};
      #pragma unroll
      for (int kt = 0; kt < 4; ++kt)
        #pragma unroll
        for (int qt = 0; qt < 2; ++qt){
          #pragma unroll
          for (int r = 0; r < 4; ++r)
            s[kt][qt][r] = __expf(s[kt][qt][r] - mrun[qt]);
          ps[qt] += vsum4(s[kt][qt]);
        }
      #pragma unroll
      for (int qt = 0; qt < 2; ++qt){
        ps[qt] += __shfl_xor(ps[qt], 16, 64);
        ps[qt] += __shfl_xor(ps[qt], 32, 64);
        lrun[qt] += ps[qt];
      }
      // ---- pack P^T to bf16 (already in 16x16x16 B-frag layout) ----
      s16x4 pb[4][2];
      #pragma unroll
      for (int kt = 0; kt < 4; ++kt)
        #pragma unroll
        for (int qt = 0; qt < 2; ++qt){
          s16x4 pv;
          #pragma unroll
          for (int r = 0; r < 4; ++r) pv[r] = (short)f2bf(s[kt][qt][r]);
          pb[kt][qt] = pv;
        }
      // ---- O^T += V^T P^T ----
      __builtin_amdgcn_s_setprio(1);
      #pragma unroll
      for (int f = 0; f < 8; ++f)
        #pragma unroll
        for (int kt = 0; kt < 4; ++kt){
          s16x4 va = *reinterpret_cast<const s16x4*>(
              &Vsm[cur][((f*16 + lr) << 6) + (((2*kt + (lg >> 1)) ^ (lr & 7)) << 3) + ((lg & 1) << 2)]);
          of[0][f] = mfma16(va, pb[kt][0], of[0][f]);
          of[1][f] = mfma16(va, pb[kt][1], of[1][f]);
        }
      __builtin_amdgcn_s_setprio(0);
    }
  }

  // ---- epilogue: O[b, q, h*128 + d], of[qt][f][r] = O^T[d=f*16+lg*4+r][q=qt*16+lr] ----
  #pragma unroll
  for (int qt = 0; qt < 2; ++qt){
    float inv = 1.0f / lrun[qt];
    #pragma unroll
    for (int f = 0; f < 8; ++f)
      #pragma unroll
      for (int r = 0; r < 4; ++r){
        int row = qrow0 + qt*16 + lr;
        int col = h * HD + f*16 + lg*4 + r;
        O[((size_t)b * LL + row) * DD + col] = f2bf(of[qt][f][r] * inv);
      }
  }
}

// ---------------- launcher ----------------
extern "C" void kernel_launch(void* const* d_in, const int* in_sizes, int n_in,
                              void* d_out, int out_size, void* d_ws, size_t ws_size,
                              hipStream_t stream)
{
  const float* x  = (const float*)d_in[0];
  const float* wq = (const float*)d_in[1];
  const float* wk = (const float*)d_in[2];
  const float* wv = (const float*)d_in[3];
  const float* wo = (const float*)d_in[4];
  float* out = (float*)d_out;

  char* p = (char*)d_ws;
  auto alloc = [&](size_t bytes) -> void* {
    void* r = (void*)p; p += (bytes + 255) & ~(size_t)255; return r;
  };
  ushort* xb    = (ushort*)alloc((size_t)Mrows * DD * 2);
  ushort* wqkvb = (ushort*)alloc((size_t)NQKV * DD * 2);
  ushort* wob   = (ushort*)alloc((size_t)DD * DD * 2);
  ushort* qws   = (ushort*)alloc((size_t)BB * NH * LL * HD * 2);
  ushort* kws   = (ushort*)alloc((size_t)BB * NKV * LL * HD * 2);
  ushort* vws   = (ushort*)alloc((size_t)BB * NKV * LL * HD * 2);  // V^T layout
  ushort* aows  = (ushort*)alloc((size_t)Mrows * DD * 2);
  float*  cosT  = (float*)alloc((size_t)LL * 64 * 4);
  float*  sinT  = (float*)alloc((size_t)LL * 64 * 4);

  hipLaunchKernelGGL(cvt_all_kernel, dim3(2048), dim3(256), 0, stream,
                     x, wq, wk, wv, wo, xb, wqkvb, wob);
  hipLaunchKernelGGL(rope_table_kernel, dim3((LL*64)/256), dim3(256), 0, stream, cosT, sinT);

  // fused QKV projection (V written transposed)
  hipLaunchKernelGGL(gemm_qkv_kernel, dim3(NQKV/128, Mrows/128), dim3(256), 0, stream,
                     xb, wqkvb, qws, kws, vws);

  // fused RoPE on Q (pre-scaled) and K
  {
    constexpr int tot = BB*NH*LL*16 + BB*NKV*LL*16;
    hipLaunchKernelGGL(rope_qk_kernel, dim3(tot/256), dim3(256), 0, stream,
                       qws, kws, cosT, sinT);
  }

  // attention
  hipLaunchKernelGGL(attn_kernel, dim3(LL/128, BB*NH), dim3(256), 0, stream,
                     qws, kws, vws, aows);

  // output projection -> fp32
  hipLaunchKernelGGL(gemm_o_kernel, dim3(DD/128, Mrows/128), dim3(256), 0, stream,
                     aows, wob, out);
}

// Round 5
// 397.026 us; speedup vs baseline: 2.7981x; 1.0152x over previous
//
#include <hip/hip_runtime.h>
#include <stdint.h>

#define DEV static __device__ __forceinline__

typedef __attribute__((ext_vector_type(8))) short s16x8;
typedef __attribute__((ext_vector_type(4))) short s16x4;
typedef __attribute__((ext_vector_type(4))) float f32x4;

constexpr int BB = 2, LL = 2048, DD = 2048, NH = 16, NKV = 4, HD = 128;
constexpr int Mrows = BB * LL;            // 4096
constexpr int NQKV = DD + 2 * NKV * HD;   // 3072

DEV ushort f2bf(float f){
  union { float f; uint32_t u; } v; v.f = f;
  uint32_t u = v.u;
  u += 0x7fffu + ((u >> 16) & 1u);
  return (ushort)(u >> 16);
}
DEV float bf2f(ushort h){
  union { uint32_t u; float f; } v; v.u = ((uint32_t)h) << 16;
  return v.f;
}

DEV f32x4 mfma32(s16x8 a, s16x8 b, f32x4 c){
  return __builtin_amdgcn_mfma_f32_16x16x32_bf16(a, b, c, 0, 0, 0);
}
DEV f32x4 mfma16(s16x4 a, s16x4 b, f32x4 c){
#if __has_builtin(__builtin_amdgcn_mfma_f32_16x16x16bf16_1k)
  return __builtin_amdgcn_mfma_f32_16x16x16bf16_1k(a, b, c, 0, 0, 0);
#else
  asm volatile("v_mfma_f32_16x16x16_bf16 %0, %1, %2, %0" : "+v"(c) : "v"(a), "v"(b));
  return c;
#endif
}

DEV float vmax4(f32x4 v){ return fmaxf(fmaxf(v[0], v[1]), fmaxf(v[2], v[3])); }
DEV float vsum4(f32x4 v){ return (v[0] + v[1]) + (v[2] + v[3]); }

// ---------------- fused fp32 -> bf16 conversion for all 5 inputs ----------------
__global__ void cvt_all_kernel(const float* __restrict__ x, const float* __restrict__ wq,
                               const float* __restrict__ wk, const float* __restrict__ wv,
                               const float* __restrict__ wo,
                               ushort* __restrict__ xb, ushort* __restrict__ wqkv,
                               ushort* __restrict__ wob){
  constexpr int C0 = Mrows * DD / 4;                 // x
  constexpr int C1 = C0 + DD * DD / 4;               // wq
  constexpr int C2 = C1 + NKV * HD * DD / 4;         // wk
  constexpr int C3 = C2 + NKV * HD * DD / 4;         // wv
  constexpr int C4 = C3 + DD * DD / 4;               // wo
  int stride = gridDim.x * blockDim.x;
  for (int i = blockIdx.x * blockDim.x + threadIdx.x; i < C4; i += stride){
    const float* src; ushort* dst; int j;
    if (i < C0){ src = x;  dst = xb;                              j = i; }
    else if (i < C1){ src = wq; dst = wqkv;                       j = i - C0; }
    else if (i < C2){ src = wk; dst = wqkv + (size_t)DD * DD;     j = i - C1; }
    else if (i < C3){ src = wv; dst = wqkv + (size_t)(DD + NKV*HD) * DD; j = i - C2; }
    else { src = wo; dst = wob;                                   j = i - C3; }
    float4 v = reinterpret_cast<const float4*>(src)[j];
    ushort4 o = make_ushort4(f2bf(v.x), f2bf(v.y), f2bf(v.z), f2bf(v.w));
    reinterpret_cast<ushort4*>(dst)[j] = o;
  }
}

// ---------------- RoPE tables: cos/sin [L][64] fp32 ----------------
__global__ void rope_table_kernel(float* __restrict__ cosT, float* __restrict__ sinT){
  int i = blockIdx.x * blockDim.x + threadIdx.x;
  if (i >= LL * 64) return;
  int l = i >> 6, f = i & 63;
  float inv = __expf(-logf(10000.f) * (float)f / 64.f);
  float ang = (float)l * inv;
  float s, c;
  sincosf(ang, &s, &c);
  cosT[i] = c; sinT[i] = s;
}

// ---------------- fused RoPE apply in place on Q and K ----------------
__global__ void rope_qk_kernel(ushort* __restrict__ q, ushort* __restrict__ k,
                               const float* __restrict__ cosT, const float* __restrict__ sinT){
  constexpr int TQ = BB * NH * LL * 16;
  constexpr int TK = BB * NKV * LL * 16;
  int idx = blockIdx.x * blockDim.x + threadIdx.x;
  if (idx >= TQ + TK) return;
  ushort* t; float scale; int id;
  if (idx < TQ){ t = q; id = idx; scale = 0.08838834764831845f; }  // 1/sqrt(128)
  else { t = k; id = idx - TQ; scale = 1.0f; }
  int c = id & 15;
  int l = (id >> 4) & (LL - 1);
  s16x8 v = *reinterpret_cast<const s16x8*>(t + (size_t)id * 8);
  int fb = (l << 6) + c * 4;
  s16x8 o;
  #pragma unroll
  for (int j = 0; j < 4; ++j){
    float x1 = bf2f((ushort)v[2*j]);
    float x2 = bf2f((ushort)v[2*j+1]);
    float co = cosT[fb + j], si = sinT[fb + j];
    o[2*j]   = (short)f2bf((x1 * co - x2 * si) * scale);
    o[2*j+1] = (short)f2bf((x1 * si + x2 * co) * scale);
  }
  *reinterpret_cast<s16x8*>(t + (size_t)id * 8) = o;
}

// ---------------- async global->LDS helper ----------------
DEV void g2l16(const void* g, void* l){
  __builtin_amdgcn_global_load_lds((__attribute__((address_space(1))) void*)(void*)g,
                                   (__attribute__((address_space(3))) void*)l, 16, 0, 0);
}

// ---------------- fused QKV GEMM: [Q|K|V] = x * Wqkv^T, scatter epilogue ----------------
// 1D grid 768, XCD-chunked swizzle: each XCD keeps 3 W-panels (1.5MB) L2-resident.
__global__ __launch_bounds__(256) void gemm_qkv_kernel(const ushort* __restrict__ A,
    const ushort* __restrict__ W, ushort* __restrict__ qo, ushort* __restrict__ ko,
    ushort* __restrict__ vo)
{
  __shared__ ushort Asm[128 * 32];
  __shared__ ushort Bsm[128 * 32];
  const int tid = threadIdx.x;
  const int lane = tid & 63;
  const int wr = tid >> 7;
  const int wc = (tid >> 6) & 1;
  const int lr = lane & 15, lg = lane >> 4;
  const int id = blockIdx.x;
  const int nid = (id & 7) * 96 + (id >> 3);   // 768 = 8 x 96
  const int bx = nid >> 5;                     // 0..23 (W panel)
  const int by = nid & 31;                     // 0..31 (A panel)
  const int brow = by * 128, bcol = bx * 128;

  f32x4 acc[4][4] = {};

  for (int kb = 0; kb < DD; kb += 32){
    #pragma unroll
    for (int it = 0; it < 2; ++it){
      int seg = it * 256 + tid;
      int row = seg >> 2, sc = seg & 3;
      g2l16(A + (size_t)(brow + row) * DD + kb + sc * 8, &Asm[seg * 8]);
    }
    #pragma unroll
    for (int it = 0; it < 2; ++it){
      int seg = it * 256 + tid;
      int row = seg >> 2, sc = seg & 3;
      g2l16(W + (size_t)(bcol + row) * DD + kb + sc * 8, &Bsm[seg * 8]);
    }
    __syncthreads();
    s16x8 af[4], bfr[4];
    #pragma unroll
    for (int m = 0; m < 4; ++m)
      af[m] = *reinterpret_cast<const s16x8*>(&Asm[(wr*64 + m*16 + lr)*32 + lg*8]);
    #pragma unroll
    for (int n = 0; n < 4; ++n)
      bfr[n] = *reinterpret_cast<const s16x8*>(&Bsm[(wc*64 + n*16 + lr)*32 + lg*8]);
    #pragma unroll
    for (int m = 0; m < 4; ++m)
      #pragma unroll
      for (int n = 0; n < 4; ++n)
        acc[m][n] = mfma32(af[m], bfr[n], acc[m][n]);
    __syncthreads();
  }

  #pragma unroll
  for (int m = 0; m < 4; ++m)
    #pragma unroll
    for (int n = 0; n < 4; ++n)
      #pragma unroll
      for (int r = 0; r < 4; ++r){
        int row = brow + wr*64 + m*16 + lg*4 + r;
        int col = bcol + wc*64 + n*16 + lr;
        int b = row >> 11, l = row & (LL - 1);
        ushort bv = f2bf(acc[m][n][r]);
        if (col < DD){
          qo[(((size_t)(b * NH + (col >> 7))) * LL + l) * HD + (col & 127)] = bv;
        } else if (col < DD + NKV * HD){
          int c = col - DD;
          ko[(((size_t)(b * NKV + (c >> 7))) * LL + l) * HD + (c & 127)] = bv;
        } else {
          int c = col - DD - NKV * HD;
          vo[(((size_t)(b * NKV + (c >> 7))) * HD + (c & 127)) * LL + l] = bv;
        }
      }
}

// ---------------- output GEMM: out = attn_out * Wo^T (fp32 out) ----------------
__global__ __launch_bounds__(256) void gemm_o_kernel(const ushort* __restrict__ A,
    const ushort* __restrict__ W, float* __restrict__ outp)
{
  __shared__ ushort Asm[128 * 32];
  __shared__ ushort Bsm[128 * 32];
  const int tid = threadIdx.x;
  const int lane = tid & 63;
  const int wr = tid >> 7;
  const int wc = (tid >> 6) & 1;
  const int lr = lane & 15, lg = lane >> 4;
  const int id = blockIdx.x;
  const int nid = (id & 7) * 64 + (id >> 3);   // 512 = 8 x 64
  const int bx = nid >> 5;                     // 0..15 (W panel)
  const int by = nid & 31;                     // 0..31
  const int brow = by * 128, bcol = bx * 128;

  f32x4 acc[4][4] = {};

  for (int kb = 0; kb < DD; kb += 32){
    #pragma unroll
    for (int it = 0; it < 2; ++it){
      int seg = it * 256 + tid;
      int row = seg >> 2, sc = seg & 3;
      g2l16(A + (size_t)(brow + row) * DD + kb + sc * 8, &Asm[seg * 8]);
    }
    #pragma unroll
    for (int it = 0; it < 2; ++it){
      int seg = it * 256 + tid;
      int row = seg >> 2, sc = seg & 3;
      g2l16(W + (size_t)(bcol + row) * DD + kb + sc * 8, &Bsm[seg * 8]);
    }
    __syncthreads();
    s16x8 af[4], bfr[4];
    #pragma unroll
    for (int m = 0; m < 4; ++m)
      af[m] = *reinterpret_cast<const s16x8*>(&Asm[(wr*64 + m*16 + lr)*32 + lg*8]);
    #pragma unroll
    for (int n = 0; n < 4; ++n)
      bfr[n] = *reinterpret_cast<const s16x8*>(&Bsm[(wc*64 + n*16 + lr)*32 + lg*8]);
    #pragma unroll
    for (int m = 0; m < 4; ++m)
      #pragma unroll
      for (int n = 0; n < 4; ++n)
        acc[m][n] = mfma32(af[m], bfr[n], acc[m][n]);
    __syncthreads();
  }

  #pragma unroll
  for (int m = 0; m < 4; ++m)
    #pragma unroll
    for (int n = 0; n < 4; ++n)
      #pragma unroll
      for (int r = 0; r < 4; ++r){
        int row = brow + wr*64 + m*16 + lg*4 + r;
        int col = bcol + wc*64 + n*16 + lr;
        outp[(size_t)row * DD + col] = acc[m][n][r];
      }
}

// ---------------- flash attention, diagonal-paired for causal balance -------------
// Each block owns q-blocks {p, 31-p} (64 rows each) => exactly 33 kv-tiles/block.
// Per wave: qt=0 -> 16 rows of low block (active t<=p); qt=1 -> 16 rows of high block.
// S^T = mfma32(K,Q); P^T C-layout == 16x16x16 B-frag layout => zero-shuffle PV.
template<int NQ>
DEV void tile_step(const ushort* __restrict__ Ks, const ushort* __restrict__ Vs,
                   const s16x8 (*qf)[4], f32x4 (*of)[8], float* mrun, float* lrun,
                   const int* qrow, int jb, int lr, int lg)
{
  f32x4 s[4][NQ];
  #pragma unroll
  for (int kt = 0; kt < 4; ++kt)
    #pragma unroll
    for (int q = 0; q < NQ; ++q) s[kt][q] = (f32x4){0.f, 0.f, 0.f, 0.f};

  __builtin_amdgcn_s_setprio(1);
  #pragma unroll
  for (int kk = 0; kk < 4; ++kk)
    #pragma unroll
    for (int kt = 0; kt < 4; ++kt){
      s16x8 kf = *reinterpret_cast<const s16x8*>(
          &Ks[((kt*16 + lr) << 7) + (((kk*4 + lg) ^ (lr & 7)) << 3)]);
      #pragma unroll
      for (int q = 0; q < NQ; ++q)
        s[kt][q] = mfma32(kf, qf[q][kk], s[kt][q]);
    }
  __builtin_amdgcn_s_setprio(0);

  // causal mask (diagonal-spanning tiles only)
  #pragma unroll
  for (int q = 0; q < NQ; ++q)
    if (jb + 63 > qrow[q]){
      int qg = qrow[q] + lr;
      #pragma unroll
      for (int kt = 0; kt < 4; ++kt){
        int kvg = jb + kt*16 + lg*4;
        #pragma unroll
        for (int r = 0; r < 4; ++r)
          if (kvg + r > qg) s[kt][q][r] = -1e30f;
      }
    }

  // row max (in-lane + 2 shuffles)
  float mx[NQ];
  #pragma unroll
  for (int q = 0; q < NQ; ++q){
    mx[q] = fmaxf(fmaxf(vmax4(s[0][q]), vmax4(s[1][q])),
                  fmaxf(vmax4(s[2][q]), vmax4(s[3][q])));
    mx[q] = fmaxf(mx[q], __shfl_xor(mx[q], 16, 64));
    mx[q] = fmaxf(mx[q], __shfl_xor(mx[q], 32, 64));
  }
  // defer-max online softmax (T13, THR=8)
  int small = 1;
  #pragma unroll
  for (int q = 0; q < NQ; ++q) small &= (mx[q] <= mrun[q] + 8.f);
  if (!__all(small)){
    #pragma unroll
    for (int q = 0; q < NQ; ++q){
      float mn = fmaxf(mrun[q], mx[q]);
      float fac = __expf(mrun[q] - mn);
      mrun[q] = mn;
      lrun[q] *= fac;
      #pragma unroll
      for (int f = 0; f < 8; ++f) of[q][f] *= fac;
    }
  }
  float ps[NQ];
  #pragma unroll
  for (int q = 0; q < NQ; ++q) ps[q] = 0.f;
  #pragma unroll
  for (int kt = 0; kt < 4; ++kt)
    #pragma unroll
    for (int q = 0; q < NQ; ++q){
      #pragma unroll
      for (int r = 0; r < 4; ++r)
        s[kt][q][r] = __expf(s[kt][q][r] - mrun[q]);
      ps[q] += vsum4(s[kt][q]);
    }
  #pragma unroll
  for (int q = 0; q < NQ; ++q){
    ps[q] += __shfl_xor(ps[q], 16, 64);
    ps[q] += __shfl_xor(ps[q], 32, 64);
    lrun[q] += ps[q];
  }
  // pack P^T to bf16 (already in 16x16x16 B-frag layout)
  s16x4 pb[4][NQ];
  #pragma unroll
  for (int kt = 0; kt < 4; ++kt)
    #pragma unroll
    for (int q = 0; q < NQ; ++q){
      s16x4 pv;
      #pragma unroll
      for (int r = 0; r < 4; ++r) pv[r] = (short)f2bf(s[kt][q][r]);
      pb[kt][q] = pv;
    }
  // O^T += V^T P^T
  __builtin_amdgcn_s_setprio(1);
  #pragma unroll
  for (int f = 0; f < 8; ++f)
    #pragma unroll
    for (int kt = 0; kt < 4; ++kt){
      s16x4 va = *reinterpret_cast<const s16x4*>(
          &Vs[((f*16 + lr) << 6) + (((2*kt + (lg >> 1)) ^ (lr & 7)) << 3) + ((lg & 1) << 2)]);
      #pragma unroll
      for (int q = 0; q < NQ; ++q)
        of[q][f] = mfma16(va, pb[kt][q], of[q][f]);
    }
  __builtin_amdgcn_s_setprio(0);
}

__global__ __launch_bounds__(256) void attn_kernel(const ushort* __restrict__ Q,
    const ushort* __restrict__ Kg, const ushort* __restrict__ VTg, ushort* __restrict__ O)
{
  __shared__ ushort Ksm[2][64 * 128];   // [kv][d] 16B chunks XOR-swizzled
  __shared__ ushort Vsm[2][128 * 64];   // [d][kv] 16B chunks XOR-swizzled
  const int tid = threadIdx.x;
  const int w = tid >> 6, lane = tid & 63;
  const int lr = lane & 15, lg = lane >> 4;
  // XCD-chunked swizzle: 512 = 8 x 64; each XCD handles one (b,kvh) K/V pair
  const int id = blockIdx.x;
  const int nid = (id & 7) * 64 + (id >> 3);
  const int pair = nid & 15;            // 0..15
  const int bh = nid >> 4;              // 0..31
  const int b = bh >> 4, h = bh & 15, kvh = h >> 2;
  const size_t qoff = (size_t)bh * LL * HD;
  const size_t koff = (size_t)(b * NKV + kvh) * LL * HD;
  const size_t voff = (size_t)(b * NKV + kvh) * HD * LL;
  const int qrow[2] = { pair*64 + w*16, (31 - pair)*64 + w*16 };
  const int nt  = 32 - pair;            // qt=1 needs tiles 0..31-pair
  const int ntA = pair + 1;             // qt=0 active tiles

  // Q B-frags: lane holds Q[qrow[qt]+lr][kk*32+lg*8 ..+7]
  s16x8 qf[2][4];
  #pragma unroll
  for (int qt = 0; qt < 2; ++qt)
    #pragma unroll
    for (int kk = 0; kk < 4; ++kk)
      qf[qt][kk] = *reinterpret_cast<const s16x8*>(
          &Q[qoff + (size_t)(qrow[qt] + lr) * HD + kk*32 + lg*8]);

  f32x4 of[2][8] = {};
  float mrun[2] = {-1e30f, -1e30f}, lrun[2] = {0.f, 0.f};

  auto STAGE = [&](int buf, int jb){
    #pragma unroll
    for (int it = 0; it < 4; ++it){
      int chunk = it * 256 + tid;
      int r = chunk >> 4, c = chunk & 15;
      g2l16(Kg + koff + (size_t)(jb + r) * HD + ((c ^ (r & 7)) << 3), &Ksm[buf][chunk << 3]);
    }
    #pragma unroll
    for (int it = 0; it < 4; ++it){
      int chunk = it * 256 + tid;
      int r = chunk >> 3, c = chunk & 7;
      g2l16(VTg + voff + (size_t)r * LL + jb + ((c ^ (r & 7)) << 3), &Vsm[buf][chunk << 3]);
    }
  };
  STAGE(0, 0);

  for (int t = 0; t < nt; ++t){
    const int jb = t << 6, cur = t & 1;
    __syncthreads();                       // drains tile-t loads (flew under compute(t-1))
    if (t + 1 < nt) STAGE(cur ^ 1, (t + 1) << 6);
    if (t < ntA)
      tile_step<2>(Ksm[cur], Vsm[cur], qf, of, mrun, lrun, qrow, jb, lr, lg);
    else
      tile_step<1>(Ksm[cur], Vsm[cur], qf + 1, of + 1, mrun + 1, lrun + 1, qrow + 1, jb, lr, lg);
  }

  // ---- epilogue: of[qt][f][r] = O^T[d=f*16+lg*4+r][q=qrow[qt]+lr] ----
  #pragma unroll
  for (int qt = 0; qt < 2; ++qt){
    float inv = 1.0f / lrun[qt];
    #pragma unroll
    for (int f = 0; f < 8; ++f)
      #pragma unroll
      for (int r = 0; r < 4; ++r){
        int row = qrow[qt] + lr;
        int col = h * HD + f*16 + lg*4 + r;
        O[((size_t)b * LL + row) * DD + col] = f2bf(of[qt][f][r] * inv);
      }
  }
}

// ---------------- launcher ----------------
extern "C" void kernel_launch(void* const* d_in, const int* in_sizes, int n_in,
                              void* d_out, int out_size, void* d_ws, size_t ws_size,
                              hipStream_t stream)
{
  const float* x  = (const float*)d_in[0];
  const float* wq = (const float*)d_in[1];
  const float* wk = (const float*)d_in[2];
  const float* wv = (const float*)d_in[3];
  const float* wo = (const float*)d_in[4];
  float* out = (float*)d_out;

  char* p = (char*)d_ws;
  auto alloc = [&](size_t bytes) -> void* {
    void* r = (void*)p; p += (bytes + 255) & ~(size_t)255; return r;
  };
  ushort* xb    = (ushort*)alloc((size_t)Mrows * DD * 2);
  ushort* wqkvb = (ushort*)alloc((size_t)NQKV * DD * 2);
  ushort* wob   = (ushort*)alloc((size_t)DD * DD * 2);
  ushort* qws   = (ushort*)alloc((size_t)BB * NH * LL * HD * 2);
  ushort* kws   = (ushort*)alloc((size_t)BB * NKV * LL * HD * 2);
  ushort* vws   = (ushort*)alloc((size_t)BB * NKV * LL * HD * 2);  // V^T layout
  ushort* aows  = (ushort*)alloc((size_t)Mrows * DD * 2);
  float*  cosT  = (float*)alloc((size_t)LL * 64 * 4);
  float*  sinT  = (float*)alloc((size_t)LL * 64 * 4);

  hipLaunchKernelGGL(cvt_all_kernel, dim3(2048), dim3(256), 0, stream,
                     x, wq, wk, wv, wo, xb, wqkvb, wob);
  hipLaunchKernelGGL(rope_table_kernel, dim3((LL*64)/256), dim3(256), 0, stream, cosT, sinT);

  // fused QKV projection (V written transposed)
  hipLaunchKernelGGL(gemm_qkv_kernel, dim3(768), dim3(256), 0, stream,
                     xb, wqkvb, qws, kws, vws);

  // fused RoPE on Q (pre-scaled) and K
  {
    constexpr int tot = BB*NH*LL*16 + BB*NKV*LL*16;
    hipLaunchKernelGGL(rope_qk_kernel, dim3(tot/256), dim3(256), 0, stream,
                       qws, kws, cosT, sinT);
  }

  // attention: diagonal-paired blocks, 33 tiles each
  hipLaunchKernelGGL(attn_kernel, dim3(512), dim3(256), 0, stream,
                     qws, kws, vws, aows);

  // output projection -> fp32
  hipLaunchKernelGGL(gemm_o_kernel, dim3(512), dim3(256), 0, stream,
                     aows, wob, out);
}

// Round 7
// 396.216 us; speedup vs baseline: 2.8039x; 1.0020x over previous
//
#include <hip/hip_runtime.h>
#include <stdint.h>

#define DEV static __device__ __forceinline__

typedef __attribute__((ext_vector_type(8))) short s16x8;
typedef __attribute__((ext_vector_type(4))) short s16x4;
typedef __attribute__((ext_vector_type(4))) float f32x4;

constexpr int BB = 2, LL = 2048, DD = 2048, NH = 16, NKV = 4, HD = 128;
constexpr int Mrows = BB * LL;            // 4096
constexpr int NQKV = DD + 2 * NKV * HD;   // 3072

DEV ushort f2bf(float f){
  union { float f; uint32_t u; } v; v.f = f;
  uint32_t u = v.u;
  u += 0x7fffu + ((u >> 16) & 1u);
  return (ushort)(u >> 16);
}
DEV float bf2f(ushort h){
  union { uint32_t u; float f; } v; v.u = ((uint32_t)h) << 16;
  return v.f;
}

DEV f32x4 mfma32(s16x8 a, s16x8 b, f32x4 c){
  return __builtin_amdgcn_mfma_f32_16x16x32_bf16(a, b, c, 0, 0, 0);
}
DEV f32x4 mfma16(s16x4 a, s16x4 b, f32x4 c){
#if __has_builtin(__builtin_amdgcn_mfma_f32_16x16x16bf16_1k)
  return __builtin_amdgcn_mfma_f32_16x16x16bf16_1k(a, b, c, 0, 0, 0);
#else
  asm volatile("v_mfma_f32_16x16x16_bf16 %0, %1, %2, %0" : "+v"(c) : "v"(a), "v"(b));
  return c;
#endif
}

DEV float vmax4(f32x4 v){ return fmaxf(fmaxf(v[0], v[1]), fmaxf(v[2], v[3])); }
DEV float vsum4(f32x4 v){ return (v[0] + v[1]) + (v[2] + v[3]); }

// ---------------- fused fp32 -> bf16 conversion for all 5 inputs ----------------
__global__ void cvt_all_kernel(const float* __restrict__ x, const float* __restrict__ wq,
                               const float* __restrict__ wk, const float* __restrict__ wv,
                               const float* __restrict__ wo,
                               ushort* __restrict__ xb, ushort* __restrict__ wqkv,
                               ushort* __restrict__ wob){
  constexpr int C0 = Mrows * DD / 4;                 // x
  constexpr int C1 = C0 + DD * DD / 4;               // wq
  constexpr int C2 = C1 + NKV * HD * DD / 4;         // wk
  constexpr int C3 = C2 + NKV * HD * DD / 4;         // wv
  constexpr int C4 = C3 + DD * DD / 4;               // wo
  int stride = gridDim.x * blockDim.x;
  for (int i = blockIdx.x * blockDim.x + threadIdx.x; i < C4; i += stride){
    const float* src; ushort* dst; int j;
    if (i < C0){ src = x;  dst = xb;                              j = i; }
    else if (i < C1){ src = wq; dst = wqkv;                       j = i - C0; }
    else if (i < C2){ src = wk; dst = wqkv + (size_t)DD * DD;     j = i - C1; }
    else if (i < C3){ src = wv; dst = wqkv + (size_t)(DD + NKV*HD) * DD; j = i - C2; }
    else { src = wo; dst = wob;                                   j = i - C3; }
    float4 v = reinterpret_cast<const float4*>(src)[j];
    ushort4 o = make_ushort4(f2bf(v.x), f2bf(v.y), f2bf(v.z), f2bf(v.w));
    reinterpret_cast<ushort4*>(dst)[j] = o;
  }
}

// ---------------- RoPE tables: cos/sin [L][64] fp32 ----------------
__global__ void rope_table_kernel(float* __restrict__ cosT, float* __restrict__ sinT){
  int i = blockIdx.x * blockDim.x + threadIdx.x;
  if (i >= LL * 64) return;
  int l = i >> 6, f = i & 63;
  float inv = __expf(-logf(10000.f) * (float)f / 64.f);
  float ang = (float)l * inv;
  float s, c;
  sincosf(ang, &s, &c);
  cosT[i] = c; sinT[i] = s;
}

// ---------------- fused RoPE apply in place on Q and K ----------------
__global__ void rope_qk_kernel(ushort* __restrict__ q, ushort* __restrict__ k,
                               const float* __restrict__ cosT, const float* __restrict__ sinT){
  constexpr int TQ = BB * NH * LL * 16;
  constexpr int TK = BB * NKV * LL * 16;
  int idx = blockIdx.x * blockDim.x + threadIdx.x;
  if (idx >= TQ + TK) return;
  ushort* t; float scale; int id;
  if (idx < TQ){ t = q; id = idx; scale = 0.08838834764831845f; }  // 1/sqrt(128)
  else { t = k; id = idx - TQ; scale = 1.0f; }
  int c = id & 15;
  int l = (id >> 4) & (LL - 1);
  s16x8 v = *reinterpret_cast<const s16x8*>(t + (size_t)id * 8);
  int fb = (l << 6) + c * 4;
  s16x8 o;
  #pragma unroll
  for (int j = 0; j < 4; ++j){
    float x1 = bf2f((ushort)v[2*j]);
    float x2 = bf2f((ushort)v[2*j+1]);
    float co = cosT[fb + j], si = sinT[fb + j];
    o[2*j]   = (short)f2bf((x1 * co - x2 * si) * scale);
    o[2*j+1] = (short)f2bf((x1 * si + x2 * co) * scale);
  }
  *reinterpret_cast<s16x8*>(t + (size_t)id * 8) = o;
}

// ---------------- async global->LDS helper ----------------
DEV void g2l16(const void* g, void* l){
  __builtin_amdgcn_global_load_lds((__attribute__((address_space(1))) void*)(void*)g,
                                   (__attribute__((address_space(3))) void*)l, 16, 0, 0);
}

// ============ 256x256 8-phase GEMM (T3+T4+T5), BK=64 in two K=32 half-slices =======
// C = A(4096 x 2048) * W(N x 2048)^T.  8 waves (2M x 4N), per-wave C = 128x64.
// LDS (dynamic 128KB): A[2 buf][2 kh][256 rows][32 k], B same. Rows are 64B.
// Stage unit = one (tensor, kh) half = 16KB = 2 gload_lds/thread. Ring schedule:
// computing tile t (phases 1-4: (kk0,mh0)(kk0,mh1)(kk1,mh0)(kk1,mh1)), t+1 (5-8):
//   p1:H(t+1,A,kh1) p2:H(t+1,B,kh1) p3:H(t+2,A,kh0) p4:H(t+2,B,kh0)+vmcnt(4)
//   p5:H(t+2,A,kh1) p6:H(t+2,B,kh1) p7:H(t+3,A,kh0) p8:H(t+3,B,kh0)+vmcnt(4)
// Every stage targets a region whose last reader phase is strictly earlier
// (>=1 barrier between), and every read is covered by a prior vmcnt(4)+barrier.
// MODE 0: fp32 out [row][2048].  MODE 1: QKV scatter (V transposed).
#define GPHASE(DB, KK, MH, SDB, SKH, SB, ST, VM) { \
    const ushort* As_ = Asm + ((DB)*2 + (KK)) * 8192 + wm * 128 * 32; \
    const ushort* Bs_ = Bsm + ((DB)*2 + (KK)) * 8192 + wn * 64 * 32; \
    s16x8 af_[4], bf_[4]; \
    _Pragma("unroll") \
    for (int i_ = 0; i_ < 4; ++i_) \
      af_[i_] = *(const s16x8*)&As_[(((MH)*4 + i_) * 16 + lr) * 32 + lg * 8]; \
    _Pragma("unroll") \
    for (int n_ = 0; n_ < 4; ++n_) \
      bf_[n_] = *(const s16x8*)&Bs_[(n_ * 16 + lr) * 32 + lg * 8]; \
    STG(SDB, SKH, SB, ST); \
    if (VM) asm volatile("s_waitcnt vmcnt(4)" ::: "memory"); \
    __builtin_amdgcn_s_barrier(); \
    __builtin_amdgcn_s_setprio(1); \
    _Pragma("unroll") \
    for (int i_ = 0; i_ < 4; ++i_) \
      _Pragma("unroll") \
      for (int n_ = 0; n_ < 4; ++n_) \
        acc[(MH)*4 + i_][n_] = mfma32(af_[i_], bf_[n_], acc[(MH)*4 + i_][n_]); \
    __builtin_amdgcn_s_setprio(0); \
    __builtin_amdgcn_s_barrier(); \
  }

template<int MODE>
__global__ __launch_bounds__(512, 2) void gemm256_kernel(const ushort* __restrict__ A,
    const ushort* __restrict__ W, float* __restrict__ fout, ushort* __restrict__ qo,
    ushort* __restrict__ ko, ushort* __restrict__ vo)
{
  extern __shared__ ushort smem[];          // 128 KB
  ushort* Asm = smem;                        // [2][2][256][32] = 32768 elems
  ushort* Bsm = smem + 32768;
  const int tid = threadIdx.x;
  const int w = tid >> 6, lane = tid & 63;
  const int lr = lane & 15, lg = lane >> 4;
  const int wm = w >> 2, wn = w & 3;
  const int cpx = (int)gridDim.x >> 3;       // blocks per XCD (grid % 8 == 0)
  const int id = (int)blockIdx.x;
  const int nid = (id & 7) * cpx + (id >> 3);
  const int bx = nid >> 4, by = nid & 15;    // W-panel-major within an XCD chunk
  const int brow = by * 256, bcol = bx * 256;

  // per-thread staging bases: 16 rows/wave-load, 4x16B chunks per row
  const ushort* gA = A + (size_t)(brow + w*32 + (lane >> 2)) * 2048 + (lane & 3) * 8;
  const ushort* gW = W + (size_t)(bcol + w*32 + (lane >> 2)) * 2048 + (lane & 3) * 8;
  const int ldsOff = w * 1024 + lane * 8;    // linear: base + lane*16B

  f32x4 acc[8][4] = {};

  auto STG = [&](int db, int kh, int isB, int tile){
    const ushort* g = (isB ? gW : gA) + tile * 64 + kh * 32;
    ushort* l = (isB ? Bsm : Asm) + (db*2 + kh) * 8192 + ldsOff;
    g2l16(g, l);
    g2l16(g + 16 * 2048, l + 512);
  };

  // prologue: tile0 complete + tile1 kh0 in flight
  STG(0,0,0,0); STG(0,0,1,0); STG(0,1,0,0); STG(0,1,1,0); STG(1,0,0,1); STG(1,0,1,1);
  asm volatile("s_waitcnt vmcnt(4)" ::: "memory");
  __builtin_amdgcn_s_barrier();

  for (int it = 0; it < 16; ++it){
    const int t  = 2 * it;
    const int t2 = (t + 2 < 32) ? t + 2 : 31;
    const int t3 = (t + 3 < 32) ? t + 3 : 31;
    GPHASE(0,0,0, 1,1,0, t+1, 0);
    GPHASE(0,0,1, 1,1,1, t+1, 0);
    GPHASE(0,1,0, 0,0,0, t2,  0);
    GPHASE(0,1,1, 0,0,1, t2,  1);
    GPHASE(1,0,0, 0,1,0, t2,  0);
    GPHASE(1,0,1, 0,1,1, t2,  0);
    GPHASE(1,1,0, 1,0,0, t3,  0);
    GPHASE(1,1,1, 1,0,1, t3,  1);
  }
  // drain remaining prefetches: gload_lds landing after endpgm could corrupt a
  // successor workgroup's LDS on this CU.
  asm volatile("s_waitcnt vmcnt(0)" ::: "memory");

  #pragma unroll
  for (int mf = 0; mf < 8; ++mf)
    #pragma unroll
    for (int nf = 0; nf < 4; ++nf)
      #pragma unroll
      for (int r = 0; r < 4; ++r){
        int row = brow + wm*128 + mf*16 + lg*4 + r;
        int col = bcol + wn*64 + nf*16 + lr;
        float v = acc[mf][nf][r];
        if (MODE == 0){
          fout[(size_t)row * DD + col] = v;
        } else {
          int b = row >> 11, l = row & (LL - 1);
          ushort bv = f2bf(v);
          if (col < DD){
            qo[(((size_t)(b * NH + (col >> 7))) * LL + l) * HD + (col & 127)] = bv;
          } else if (col < DD + NKV * HD){
            int c = col - DD;
            ko[(((size_t)(b * NKV + (c >> 7))) * LL + l) * HD + (c & 127)] = bv;
          } else {
            int c = col - DD - NKV * HD;
            vo[(((size_t)(b * NKV + (c >> 7))) * HD + (c & 127)) * LL + l] = bv;
          }
        }
      }
}

// ---------------- flash attention, diagonal-paired for causal balance -------------
// (unchanged from round 5)
template<int NQ>
DEV void tile_step(const ushort* __restrict__ Ks, const ushort* __restrict__ Vs,
                   const s16x8 (*qf)[4], f32x4 (*of)[8], float* mrun, float* lrun,
                   const int* qrow, int jb, int lr, int lg)
{
  f32x4 s[4][NQ];
  #pragma unroll
  for (int kt = 0; kt < 4; ++kt)
    #pragma unroll
    for (int q = 0; q < NQ; ++q) s[kt][q] = (f32x4){0.f, 0.f, 0.f, 0.f};

  __builtin_amdgcn_s_setprio(1);
  #pragma unroll
  for (int kk = 0; kk < 4; ++kk)
    #pragma unroll
    for (int kt = 0; kt < 4; ++kt){
      s16x8 kf = *reinterpret_cast<const s16x8*>(
          &Ks[((kt*16 + lr) << 7) + (((kk*4 + lg) ^ (lr & 7)) << 3)]);
      #pragma unroll
      for (int q = 0; q < NQ; ++q)
        s[kt][q] = mfma32(kf, qf[q][kk], s[kt][q]);
    }
  __builtin_amdgcn_s_setprio(0);

  #pragma unroll
  for (int q = 0; q < NQ; ++q)
    if (jb + 63 > qrow[q]){
      int qg = qrow[q] + lr;
      #pragma unroll
      for (int kt = 0; kt < 4; ++kt){
        int kvg = jb + kt*16 + lg*4;
        #pragma unroll
        for (int r = 0; r < 4; ++r)
          if (kvg + r > qg) s[kt][q][r] = -1e30f;
      }
    }

  float mx[NQ];
  #pragma unroll
  for (int q = 0; q < NQ; ++q){
    mx[q] = fmaxf(fmaxf(vmax4(s[0][q]), vmax4(s[1][q])),
                  fmaxf(vmax4(s[2][q]), vmax4(s[3][q])));
    mx[q] = fmaxf(mx[q], __shfl_xor(mx[q], 16, 64));
    mx[q] = fmaxf(mx[q], __shfl_xor(mx[q], 32, 64));
  }
  int small = 1;
  #pragma unroll
  for (int q = 0; q < NQ; ++q) small &= (mx[q] <= mrun[q] + 8.f);
  if (!__all(small)){
    #pragma unroll
    for (int q = 0; q < NQ; ++q){
      float mn = fmaxf(mrun[q], mx[q]);
      float fac = __expf(mrun[q] - mn);
      mrun[q] = mn;
      lrun[q] *= fac;
      #pragma unroll
      for (int f = 0; f < 8; ++f) of[q][f] *= fac;
    }
  }
  float ps[NQ];
  #pragma unroll
  for (int q = 0; q < NQ; ++q) ps[q] = 0.f;
  #pragma unroll
  for (int kt = 0; kt < 4; ++kt)
    #pragma unroll
    for (int q = 0; q < NQ; ++q){
      #pragma unroll
      for (int r = 0; r < 4; ++r)
        s[kt][q][r] = __expf(s[kt][q][r] - mrun[q]);
      ps[q] += vsum4(s[kt][q]);
    }
  #pragma unroll
  for (int q = 0; q < NQ; ++q){
    ps[q] += __shfl_xor(ps[q], 16, 64);
    ps[q] += __shfl_xor(ps[q], 32, 64);
    lrun[q] += ps[q];
  }
  s16x4 pb[4][NQ];
  #pragma unroll
  for (int kt = 0; kt < 4; ++kt)
    #pragma unroll
    for (int q = 0; q < NQ; ++q){
      s16x4 pv;
      #pragma unroll
      for (int r = 0; r < 4; ++r) pv[r] = (short)f2bf(s[kt][q][r]);
      pb[kt][q] = pv;
    }
  __builtin_amdgcn_s_setprio(1);
  #pragma unroll
  for (int f = 0; f < 8; ++f)
    #pragma unroll
    for (int kt = 0; kt < 4; ++kt){
      s16x4 va = *reinterpret_cast<const s16x4*>(
          &Vs[((f*16 + lr) << 6) + (((2*kt + (lg >> 1)) ^ (lr & 7)) << 3) + ((lg & 1) << 2)]);
      #pragma unroll
      for (int q = 0; q < NQ; ++q)
        of[q][f] = mfma16(va, pb[kt][q], of[q][f]);
    }
  __builtin_amdgcn_s_setprio(0);
}

__global__ __launch_bounds__(256) void attn_kernel(const ushort* __restrict__ Q,
    const ushort* __restrict__ Kg, const ushort* __restrict__ VTg, ushort* __restrict__ O)
{
  __shared__ ushort Ksm[2][64 * 128];
  __shared__ ushort Vsm[2][128 * 64];
  const int tid = threadIdx.x;
  const int w = tid >> 6, lane = tid & 63;
  const int lr = lane & 15, lg = lane >> 4;
  const int id = blockIdx.x;
  const int nid = (id & 7) * 64 + (id >> 3);
  const int pair = nid & 15;
  const int bh = nid >> 4;
  const int b = bh >> 4, h = bh & 15, kvh = h >> 2;
  const size_t qoff = (size_t)bh * LL * HD;
  const size_t koff = (size_t)(b * NKV + kvh) * LL * HD;
  const size_t voff = (size_t)(b * NKV + kvh) * HD * LL;
  const int qrow[2] = { pair*64 + w*16, (31 - pair)*64 + w*16 };
  const int nt  = 32 - pair;
  const int ntA = pair + 1;

  s16x8 qf[2][4];
  #pragma unroll
  for (int qt = 0; qt < 2; ++qt)
    #pragma unroll
    for (int kk = 0; kk < 4; ++kk)
      qf[qt][kk] = *reinterpret_cast<const s16x8*>(
          &Q[qoff + (size_t)(qrow[qt] + lr) * HD + kk*32 + lg*8]);

  f32x4 of[2][8] = {};
  float mrun[2] = {-1e30f, -1e30f}, lrun[2] = {0.f, 0.f};

  auto STAGE = [&](int buf, int jb){
    #pragma unroll
    for (int it = 0; it < 4; ++it){
      int chunk = it * 256 + tid;
      int r = chunk >> 4, c = chunk & 15;
      g2l16(Kg + koff + (size_t)(jb + r) * HD + ((c ^ (r & 7)) << 3), &Ksm[buf][chunk << 3]);
    }
    #pragma unroll
    for (int it = 0; it < 4; ++it){
      int chunk = it * 256 + tid;
      int r = chunk >> 3, c = chunk & 7;
      g2l16(VTg + voff + (size_t)r * LL + jb + ((c ^ (r & 7)) << 3), &Vsm[buf][chunk << 3]);
    }
  };
  STAGE(0, 0);

  for (int t = 0; t < nt; ++t){
    const int jb = t << 6, cur = t & 1;
    __syncthreads();
    if (t + 1 < nt) STAGE(cur ^ 1, (t + 1) << 6);
    if (t < ntA)
      tile_step<2>(Ksm[cur], Vsm[cur], qf, of, mrun, lrun, qrow, jb, lr, lg);
    else
      tile_step<1>(Ksm[cur], Vsm[cur], qf + 1, of + 1, mrun + 1, lrun + 1, qrow + 1, jb, lr, lg);
  }

  #pragma unroll
  for (int qt = 0; qt < 2; ++qt){
    float inv = 1.0f / lrun[qt];
    #pragma unroll
    for (int f = 0; f < 8; ++f)
      #pragma unroll
      for (int r = 0; r < 4; ++r){
        int row = qrow[qt] + lr;
        int col = h * HD + f*16 + lg*4 + r;
        O[((size_t)b * LL + row) * DD + col] = f2bf(of[qt][f][r] * inv);
      }
  }
}

// ---------------- launcher ----------------
extern "C" void kernel_launch(void* const* d_in, const int* in_sizes, int n_in,
                              void* d_out, int out_size, void* d_ws, size_t ws_size,
                              hipStream_t stream)
{
  const float* x  = (const float*)d_in[0];
  const float* wq = (const float*)d_in[1];
  const float* wk = (const float*)d_in[2];
  const float* wv = (const float*)d_in[3];
  const float* wo = (const float*)d_in[4];
  float* out = (float*)d_out;

  char* p = (char*)d_ws;
  auto alloc = [&](size_t bytes) -> void* {
    void* r = (void*)p; p += (bytes + 255) & ~(size_t)255; return r;
  };
  ushort* xb    = (ushort*)alloc((size_t)Mrows * DD * 2);
  ushort* wqkvb = (ushort*)alloc((size_t)NQKV * DD * 2);
  ushort* wob   = (ushort*)alloc((size_t)DD * DD * 2);
  ushort* qws   = (ushort*)alloc((size_t)BB * NH * LL * HD * 2);
  ushort* kws   = (ushort*)alloc((size_t)BB * NKV * LL * HD * 2);
  ushort* vws   = (ushort*)alloc((size_t)BB * NKV * LL * HD * 2);  // V^T layout
  ushort* aows  = (ushort*)alloc((size_t)Mrows * DD * 2);
  float*  cosT  = (float*)alloc((size_t)LL * 64 * 4);
  float*  sinT  = (float*)alloc((size_t)LL * 64 * 4);

  hipFuncSetAttribute(reinterpret_cast<const void*>(gemm256_kernel<1>),
                      hipFuncAttributeMaxDynamicSharedMemorySize, 131072);
  hipFuncSetAttribute(reinterpret_cast<const void*>(gemm256_kernel<0>),
                      hipFuncAttributeMaxDynamicSharedMemorySize, 131072);

  hipLaunchKernelGGL(cvt_all_kernel, dim3(2048), dim3(256), 0, stream,
                     x, wq, wk, wv, wo, xb, wqkvb, wob);
  hipLaunchKernelGGL(rope_table_kernel, dim3((LL*64)/256), dim3(256), 0, stream, cosT, sinT);

  // fused QKV projection, 256^2 8-phase (V written transposed): 12x16 = 192 blocks
  hipLaunchKernelGGL(gemm256_kernel<1>, dim3(192), dim3(512), 131072, stream,
                     xb, wqkvb, (float*)nullptr, qws, kws, vws);

  // fused RoPE on Q (pre-scaled) and K
  {
    constexpr int tot = BB*NH*LL*16 + BB*NKV*LL*16;
    hipLaunchKernelGGL(rope_qk_kernel, dim3(tot/256), dim3(256), 0, stream,
                       qws, kws, cosT, sinT);
  }

  // attention: diagonal-paired blocks, 33 tiles each
  hipLaunchKernelGGL(attn_kernel, dim3(512), dim3(256), 0, stream,
                     qws, kws, vws, aows);

  // output projection, 256^2 8-phase -> fp32: 8x16 = 128 blocks
  hipLaunchKernelGGL(gemm256_kernel<0>, dim3(128), dim3(512), 131072, stream,
                     aows, wob, out, (ushort*)nullptr, (ushort*)nullptr, (ushort*)nullptr);
}

// Round 8
// 375.007 us; speedup vs baseline: 2.9624x; 1.0566x over previous
//
#include <hip/hip_runtime.h>
#include <stdint.h>

#define DEV static __device__ __forceinline__

typedef __attribute__((ext_vector_type(8))) short s16x8;
typedef __attribute__((ext_vector_type(4))) short s16x4;
typedef __attribute__((ext_vector_type(4))) float f32x4;

constexpr int BB = 2, LL = 2048, DD = 2048, NH = 16, NKV = 4, HD = 128;
constexpr int Mrows = BB * LL;            // 4096
constexpr int NQKV = DD + 2 * NKV * HD;   // 3072

DEV ushort f2bf(float f){
  union { float f; uint32_t u; } v; v.f = f;
  uint32_t u = v.u;
  u += 0x7fffu + ((u >> 16) & 1u);
  return (ushort)(u >> 16);
}
DEV float bf2f(ushort h){
  union { uint32_t u; float f; } v; v.u = ((uint32_t)h) << 16;
  return v.f;
}

DEV f32x4 mfma32(s16x8 a, s16x8 b, f32x4 c){
  return __builtin_amdgcn_mfma_f32_16x16x32_bf16(a, b, c, 0, 0, 0);
}
DEV f32x4 mfma16(s16x4 a, s16x4 b, f32x4 c){
#if __has_builtin(__builtin_amdgcn_mfma_f32_16x16x16bf16_1k)
  return __builtin_amdgcn_mfma_f32_16x16x16bf16_1k(a, b, c, 0, 0, 0);
#else
  asm volatile("v_mfma_f32_16x16x16_bf16 %0, %1, %2, %0" : "+v"(c) : "v"(a), "v"(b));
  return c;
#endif
}

DEV float vmax4(f32x4 v){ return fmaxf(fmaxf(v[0], v[1]), fmaxf(v[2], v[3])); }
DEV float vsum4(f32x4 v){ return (v[0] + v[1]) + (v[2] + v[3]); }

// ---------------- fused fp32 -> bf16 conversion for all 5 inputs ----------------
__global__ void cvt_all_kernel(const float* __restrict__ x, const float* __restrict__ wq,
                               const float* __restrict__ wk, const float* __restrict__ wv,
                               const float* __restrict__ wo,
                               ushort* __restrict__ xb, ushort* __restrict__ wqkv,
                               ushort* __restrict__ wob){
  constexpr int C0 = Mrows * DD / 4;                 // x
  constexpr int C1 = C0 + DD * DD / 4;               // wq
  constexpr int C2 = C1 + NKV * HD * DD / 4;         // wk
  constexpr int C3 = C2 + NKV * HD * DD / 4;         // wv
  constexpr int C4 = C3 + DD * DD / 4;               // wo
  int stride = gridDim.x * blockDim.x;
  for (int i = blockIdx.x * blockDim.x + threadIdx.x; i < C4; i += stride){
    const float* src; ushort* dst; int j;
    if (i < C0){ src = x;  dst = xb;                              j = i; }
    else if (i < C1){ src = wq; dst = wqkv;                       j = i - C0; }
    else if (i < C2){ src = wk; dst = wqkv + (size_t)DD * DD;     j = i - C1; }
    else if (i < C3){ src = wv; dst = wqkv + (size_t)(DD + NKV*HD) * DD; j = i - C2; }
    else { src = wo; dst = wob;                                   j = i - C3; }
    float4 v = reinterpret_cast<const float4*>(src)[j];
    ushort4 o = make_ushort4(f2bf(v.x), f2bf(v.y), f2bf(v.z), f2bf(v.w));
    reinterpret_cast<ushort4*>(dst)[j] = o;
  }
}

// ---------------- RoPE tables: cos/sin [L][64] fp32 ----------------
__global__ void rope_table_kernel(float* __restrict__ cosT, float* __restrict__ sinT){
  int i = blockIdx.x * blockDim.x + threadIdx.x;
  if (i >= LL * 64) return;
  int l = i >> 6, f = i & 63;
  float inv = __expf(-logf(10000.f) * (float)f / 64.f);
  float ang = (float)l * inv;
  float s, c;
  sincosf(ang, &s, &c);
  cosT[i] = c; sinT[i] = s;
}

// ---------------- fused RoPE apply in place on Q and K ----------------
__global__ void rope_qk_kernel(ushort* __restrict__ q, ushort* __restrict__ k,
                               const float* __restrict__ cosT, const float* __restrict__ sinT){
  constexpr int TQ = BB * NH * LL * 16;
  constexpr int TK = BB * NKV * LL * 16;
  int idx = blockIdx.x * blockDim.x + threadIdx.x;
  if (idx >= TQ + TK) return;
  ushort* t; float scale; int id;
  if (idx < TQ){ t = q; id = idx; scale = 0.08838834764831845f; }  // 1/sqrt(128)
  else { t = k; id = idx - TQ; scale = 1.0f; }
  int c = id & 15;
  int l = (id >> 4) & (LL - 1);
  s16x8 v = *reinterpret_cast<const s16x8*>(t + (size_t)id * 8);
  int fb = (l << 6) + c * 4;
  s16x8 o;
  #pragma unroll
  for (int j = 0; j < 4; ++j){
    float x1 = bf2f((ushort)v[2*j]);
    float x2 = bf2f((ushort)v[2*j+1]);
    float co = cosT[fb + j], si = sinT[fb + j];
    o[2*j]   = (short)f2bf((x1 * co - x2 * si) * scale);
    o[2*j+1] = (short)f2bf((x1 * si + x2 * co) * scale);
  }
  *reinterpret_cast<s16x8*>(t + (size_t)id * 8) = o;
}

// ---------------- async global->LDS helper ----------------
DEV void g2l16(const void* g, void* l){
  __builtin_amdgcn_global_load_lds((__attribute__((address_space(1))) void*)(void*)g,
                                   (__attribute__((address_space(3))) void*)l, 16, 0, 0);
}

// ============ 256x256 8-phase GEMM (T3+T4+T5+T2), BK=64 as two K=32 half-slices =====
// C = A(4096 x 2048) * W(N x 2048)^T.  8 waves (2M x 4N), per-wave C = 128x64.
// LDS (dynamic 128KB): A[2 buf][2 kh][256 rows][32 k], B same. Rows = 64B = 4 chunks.
// T2 swizzle: LDS(row, chunk) holds logical (row, chunk ^ ((row>>1)&3)) — applied as
// pre-swizzled GLOBAL source (gload_lds dest linear, rule #21) + XOR on frag reads.
// Kills the 8-way ds_read_b128 bank conflict of the unswizzled layout (r7 neutral).
// Ring schedule (verified r7): phases p1..p8 stage
//   p1:H(t+1,A,kh1) p2:H(t+1,B,kh1) p3:H(t+2,A,kh0) p4:H(t+2,B,kh0)+vmcnt(4)
//   p5:H(t+2,A,kh1) p6:H(t+2,B,kh1) p7:H(t+3,A,kh0) p8:H(t+3,B,kh0)+vmcnt(4)
// MODE 0: fp32 out [row][2048].  MODE 1: QKV scatter (V transposed).
#define GPHASE(DB, KK, MH, SDB, SKH, SB, ST, VM) { \
    const ushort* As_ = Asm + ((DB)*2 + (KK)) * 8192 + wm * 128 * 32; \
    const ushort* Bs_ = Bsm + ((DB)*2 + (KK)) * 8192 + wn * 64 * 32; \
    s16x8 af_[4], bf_[4]; \
    _Pragma("unroll") \
    for (int i_ = 0; i_ < 4; ++i_) \
      af_[i_] = *(const s16x8*)&As_[(((MH)*4 + i_) * 16 + lr) * 32 + swz]; \
    _Pragma("unroll") \
    for (int n_ = 0; n_ < 4; ++n_) \
      bf_[n_] = *(const s16x8*)&Bs_[(n_ * 16 + lr) * 32 + swz]; \
    STG(SDB, SKH, SB, ST); \
    if (VM) asm volatile("s_waitcnt vmcnt(4)" ::: "memory"); \
    __builtin_amdgcn_s_barrier(); \
    __builtin_amdgcn_s_setprio(1); \
    _Pragma("unroll") \
    for (int i_ = 0; i_ < 4; ++i_) \
      _Pragma("unroll") \
      for (int n_ = 0; n_ < 4; ++n_) \
        acc[(MH)*4 + i_][n_] = mfma32(af_[i_], bf_[n_], acc[(MH)*4 + i_][n_]); \
    __builtin_amdgcn_s_setprio(0); \
    __builtin_amdgcn_s_barrier(); \
  }

template<int MODE>
__global__ __launch_bounds__(512, 2) void gemm256_kernel(const ushort* __restrict__ A,
    const ushort* __restrict__ W, float* __restrict__ fout, ushort* __restrict__ qo,
    ushort* __restrict__ ko, ushort* __restrict__ vo)
{
  extern __shared__ ushort smem[];          // 128 KB
  ushort* Asm = smem;                        // [2][2][256][32] = 32768 elems
  ushort* Bsm = smem + 32768;
  const int tid = threadIdx.x;
  const int w = tid >> 6, lane = tid & 63;
  const int lr = lane & 15, lg = lane >> 4;
  const int wm = w >> 2, wn = w & 3;
  // read-side swizzle: chunk' = lg ^ ((row>>1)&3); row bases (wm*128, wn*64, MH*64,
  // n*16) are all == 0 mod 4 rows, so only lr contributes: (lr>>1)&3.
  const int swz = (lg ^ ((lr >> 1) & 3)) * 8;
  const int cpx = (int)gridDim.x >> 3;       // blocks per XCD (grid % 8 == 0)
  const int id = (int)blockIdx.x;
  const int nid = (id & 7) * cpx + (id >> 3);
  const int bx = nid >> 4, by = nid & 15;    // W-panel-major within an XCD chunk
  const int brow = by * 256, bcol = bx * 256;

  // staging: dest (row = w*32 + lane>>2, chunk = lane&3); source chunk pre-swizzled
  // by ((row>>1)&3) = ((lane>>3)&3)  (w*32 and +16 rows are both == 0 mod 4).
  const int schunk = ((lane & 3) ^ ((lane >> 3) & 3)) * 8;
  const ushort* gA = A + (size_t)(brow + w*32 + (lane >> 2)) * 2048 + schunk;
  const ushort* gW = W + (size_t)(bcol + w*32 + (lane >> 2)) * 2048 + schunk;
  const int ldsOff = w * 1024 + lane * 8;    // linear: base + lane*16B

  f32x4 acc[8][4] = {};

  auto STG = [&](int db, int kh, int isB, int tile){
    const ushort* g = (isB ? gW : gA) + tile * 64 + kh * 32;
    ushort* l = (isB ? Bsm : Asm) + (db*2 + kh) * 8192 + ldsOff;
    g2l16(g, l);
    g2l16(g + 16 * 2048, l + 512);
  };

  // prologue: tile0 complete + tile1 kh0 in flight
  STG(0,0,0,0); STG(0,0,1,0); STG(0,1,0,0); STG(0,1,1,0); STG(1,0,0,1); STG(1,0,1,1);
  asm volatile("s_waitcnt vmcnt(4)" ::: "memory");
  __builtin_amdgcn_s_barrier();

  for (int it = 0; it < 16; ++it){
    const int t  = 2 * it;
    const int t2 = (t + 2 < 32) ? t + 2 : 31;
    const int t3 = (t + 3 < 32) ? t + 3 : 31;
    GPHASE(0,0,0, 1,1,0, t+1, 0);
    GPHASE(0,0,1, 1,1,1, t+1, 0);
    GPHASE(0,1,0, 0,0,0, t2,  0);
    GPHASE(0,1,1, 0,0,1, t2,  1);
    GPHASE(1,0,0, 0,1,0, t2,  0);
    GPHASE(1,0,1, 0,1,1, t2,  0);
    GPHASE(1,1,0, 1,0,0, t3,  0);
    GPHASE(1,1,1, 1,0,1, t3,  1);
  }
  // drain remaining prefetches: gload_lds landing after endpgm could corrupt a
  // successor workgroup's LDS on this CU.
  asm volatile("s_waitcnt vmcnt(0)" ::: "memory");

  #pragma unroll
  for (int mf = 0; mf < 8; ++mf)
    #pragma unroll
    for (int nf = 0; nf < 4; ++nf)
      #pragma unroll
      for (int r = 0; r < 4; ++r){
        int row = brow + wm*128 + mf*16 + lg*4 + r;
        int col = bcol + wn*64 + nf*16 + lr;
        float v = acc[mf][nf][r];
        if (MODE == 0){
          fout[(size_t)row * DD + col] = v;
        } else {
          int b = row >> 11, l = row & (LL - 1);
          ushort bv = f2bf(v);
          if (col < DD){
            qo[(((size_t)(b * NH + (col >> 7))) * LL + l) * HD + (col & 127)] = bv;
          } else if (col < DD + NKV * HD){
            int c = col - DD;
            ko[(((size_t)(b * NKV + (c >> 7))) * LL + l) * HD + (c & 127)] = bv;
          } else {
            int c = col - DD - NKV * HD;
            vo[(((size_t)(b * NKV + (c >> 7))) * HD + (c & 127)) * LL + l] = bv;
          }
        }
      }
}

// ---------------- flash attention, diagonal-paired for causal balance -------------
// (unchanged from round 7)
template<int NQ>
DEV void tile_step(const ushort* __restrict__ Ks, const ushort* __restrict__ Vs,
                   const s16x8 (*qf)[4], f32x4 (*of)[8], float* mrun, float* lrun,
                   const int* qrow, int jb, int lr, int lg)
{
  f32x4 s[4][NQ];
  #pragma unroll
  for (int kt = 0; kt < 4; ++kt)
    #pragma unroll
    for (int q = 0; q < NQ; ++q) s[kt][q] = (f32x4){0.f, 0.f, 0.f, 0.f};

  __builtin_amdgcn_s_setprio(1);
  #pragma unroll
  for (int kk = 0; kk < 4; ++kk)
    #pragma unroll
    for (int kt = 0; kt < 4; ++kt){
      s16x8 kf = *reinterpret_cast<const s16x8*>(
          &Ks[((kt*16 + lr) << 7) + (((kk*4 + lg) ^ (lr & 7)) << 3)]);
      #pragma unroll
      for (int q = 0; q < NQ; ++q)
        s[kt][q] = mfma32(kf, qf[q][kk], s[kt][q]);
    }
  __builtin_amdgcn_s_setprio(0);

  #pragma unroll
  for (int q = 0; q < NQ; ++q)
    if (jb + 63 > qrow[q]){
      int qg = qrow[q] + lr;
      #pragma unroll
      for (int kt = 0; kt < 4; ++kt){
        int kvg = jb + kt*16 + lg*4;
        #pragma unroll
        for (int r = 0; r < 4; ++r)
          if (kvg + r > qg) s[kt][q][r] = -1e30f;
      }
    }

  float mx[NQ];
  #pragma unroll
  for (int q = 0; q < NQ; ++q){
    mx[q] = fmaxf(fmaxf(vmax4(s[0][q]), vmax4(s[1][q])),
                  fmaxf(vmax4(s[2][q]), vmax4(s[3][q])));
    mx[q] = fmaxf(mx[q], __shfl_xor(mx[q], 16, 64));
    mx[q] = fmaxf(mx[q], __shfl_xor(mx[q], 32, 64));
  }
  int small = 1;
  #pragma unroll
  for (int q = 0; q < NQ; ++q) small &= (mx[q] <= mrun[q] + 8.f);
  if (!__all(small)){
    #pragma unroll
    for (int q = 0; q < NQ; ++q){
      float mn = fmaxf(mrun[q], mx[q]);
      float fac = __expf(mrun[q] - mn);
      mrun[q] = mn;
      lrun[q] *= fac;
      #pragma unroll
      for (int f = 0; f < 8; ++f) of[q][f] *= fac;
    }
  }
  float ps[NQ];
  #pragma unroll
  for (int q = 0; q < NQ; ++q) ps[q] = 0.f;
  #pragma unroll
  for (int kt = 0; kt < 4; ++kt)
    #pragma unroll
    for (int q = 0; q < NQ; ++q){
      #pragma unroll
      for (int r = 0; r < 4; ++r)
        s[kt][q][r] = __expf(s[kt][q][r] - mrun[q]);
      ps[q] += vsum4(s[kt][q]);
    }
  #pragma unroll
  for (int q = 0; q < NQ; ++q){
    ps[q] += __shfl_xor(ps[q], 16, 64);
    ps[q] += __shfl_xor(ps[q], 32, 64);
    lrun[q] += ps[q];
  }
  s16x4 pb[4][NQ];
  #pragma unroll
  for (int kt = 0; kt < 4; ++kt)
    #pragma unroll
    for (int q = 0; q < NQ; ++q){
      s16x4 pv;
      #pragma unroll
      for (int r = 0; r < 4; ++r) pv[r] = (short)f2bf(s[kt][q][r]);
      pb[kt][q] = pv;
    }
  __builtin_amdgcn_s_setprio(1);
  #pragma unroll
  for (int f = 0; f < 8; ++f)
    #pragma unroll
    for (int kt = 0; kt < 4; ++kt){
      s16x4 va = *reinterpret_cast<const s16x4*>(
          &Vs[((f*16 + lr) << 6) + (((2*kt + (lg >> 1)) ^ (lr & 7)) << 3) + ((lg & 1) << 2)]);
      #pragma unroll
      for (int q = 0; q < NQ; ++q)
        of[q][f] = mfma16(va, pb[kt][q], of[q][f]);
    }
  __builtin_amdgcn_s_setprio(0);
}

__global__ __launch_bounds__(256) void attn_kernel(const ushort* __restrict__ Q,
    const ushort* __restrict__ Kg, const ushort* __restrict__ VTg, ushort* __restrict__ O)
{
  __shared__ ushort Ksm[2][64 * 128];
  __shared__ ushort Vsm[2][128 * 64];
  const int tid = threadIdx.x;
  const int w = tid >> 6, lane = tid & 63;
  const int lr = lane & 15, lg = lane >> 4;
  const int id = blockIdx.x;
  const int nid = (id & 7) * 64 + (id >> 3);
  const int pair = nid & 15;
  const int bh = nid >> 4;
  const int b = bh >> 4, h = bh & 15, kvh = h >> 2;
  const size_t qoff = (size_t)bh * LL * HD;
  const size_t koff = (size_t)(b * NKV + kvh) * LL * HD;
  const size_t voff = (size_t)(b * NKV + kvh) * HD * LL;
  const int qrow[2] = { pair*64 + w*16, (31 - pair)*64 + w*16 };
  const int nt  = 32 - pair;
  const int ntA = pair + 1;

  s16x8 qf[2][4];
  #pragma unroll
  for (int qt = 0; qt < 2; ++qt)
    #pragma unroll
    for (int kk = 0; kk < 4; ++kk)
      qf[qt][kk] = *reinterpret_cast<const s16x8*>(
          &Q[qoff + (size_t)(qrow[qt] + lr) * HD + kk*32 + lg*8]);

  f32x4 of[2][8] = {};
  float mrun[2] = {-1e30f, -1e30f}, lrun[2] = {0.f, 0.f};

  auto STAGE = [&](int buf, int jb){
    #pragma unroll
    for (int it = 0; it < 4; ++it){
      int chunk = it * 256 + tid;
      int r = chunk >> 4, c = chunk & 15;
      g2l16(Kg + koff + (size_t)(jb + r) * HD + ((c ^ (r & 7)) << 3), &Ksm[buf][chunk << 3]);
    }
    #pragma unroll
    for (int it = 0; it < 4; ++it){
      int chunk = it * 256 + tid;
      int r = chunk >> 3, c = chunk & 7;
      g2l16(VTg + voff + (size_t)r * LL + jb + ((c ^ (r & 7)) << 3), &Vsm[buf][chunk << 3]);
    }
  };
  STAGE(0, 0);

  for (int t = 0; t < nt; ++t){
    const int jb = t << 6, cur = t & 1;
    __syncthreads();
    if (t + 1 < nt) STAGE(cur ^ 1, (t + 1) << 6);
    if (t < ntA)
      tile_step<2>(Ksm[cur], Vsm[cur], qf, of, mrun, lrun, qrow, jb, lr, lg);
    else
      tile_step<1>(Ksm[cur], Vsm[cur], qf + 1, of + 1, mrun + 1, lrun + 1, qrow + 1, jb, lr, lg);
  }

  #pragma unroll
  for (int qt = 0; qt < 2; ++qt){
    float inv = 1.0f / lrun[qt];
    #pragma unroll
    for (int f = 0; f < 8; ++f)
      #pragma unroll
      for (int r = 0; r < 4; ++r){
        int row = qrow[qt] + lr;
        int col = h * HD + f*16 + lg*4 + r;
        O[((size_t)b * LL + row) * DD + col] = f2bf(of[qt][f][r] * inv);
      }
  }
}

// ---------------- launcher ----------------
extern "C" void kernel_launch(void* const* d_in, const int* in_sizes, int n_in,
                              void* d_out, int out_size, void* d_ws, size_t ws_size,
                              hipStream_t stream)
{
  const float* x  = (const float*)d_in[0];
  const float* wq = (const float*)d_in[1];
  const float* wk = (const float*)d_in[2];
  const float* wv = (const float*)d_in[3];
  const float* wo = (const float*)d_in[4];
  float* out = (float*)d_out;

  char* p = (char*)d_ws;
  auto alloc = [&](size_t bytes) -> void* {
    void* r = (void*)p; p += (bytes + 255) & ~(size_t)255; return r;
  };
  ushort* xb    = (ushort*)alloc((size_t)Mrows * DD * 2);
  ushort* wqkvb = (ushort*)alloc((size_t)NQKV * DD * 2);
  ushort* wob   = (ushort*)alloc((size_t)DD * DD * 2);
  ushort* qws   = (ushort*)alloc((size_t)BB * NH * LL * HD * 2);
  ushort* kws   = (ushort*)alloc((size_t)BB * NKV * LL * HD * 2);
  ushort* vws   = (ushort*)alloc((size_t)BB * NKV * LL * HD * 2);  // V^T layout
  ushort* aows  = (ushort*)alloc((size_t)Mrows * DD * 2);
  float*  cosT  = (float*)alloc((size_t)LL * 64 * 4);
  float*  sinT  = (float*)alloc((size_t)LL * 64 * 4);

  hipFuncSetAttribute(reinterpret_cast<const void*>(gemm256_kernel<1>),
                      hipFuncAttributeMaxDynamicSharedMemorySize, 131072);
  hipFuncSetAttribute(reinterpret_cast<const void*>(gemm256_kernel<0>),
                      hipFuncAttributeMaxDynamicSharedMemorySize, 131072);

  hipLaunchKernelGGL(cvt_all_kernel, dim3(2048), dim3(256), 0, stream,
                     x, wq, wk, wv, wo, xb, wqkvb, wob);
  hipLaunchKernelGGL(rope_table_kernel, dim3((LL*64)/256), dim3(256), 0, stream, cosT, sinT);

  // fused QKV projection, 256^2 8-phase (V written transposed): 12x16 = 192 blocks
  hipLaunchKernelGGL(gemm256_kernel<1>, dim3(192), dim3(512), 131072, stream,
                     xb, wqkvb, (float*)nullptr, qws, kws, vws);

  // fused RoPE on Q (pre-scaled) and K
  {
    constexpr int tot = BB*NH*LL*16 + BB*NKV*LL*16;
    hipLaunchKernelGGL(rope_qk_kernel, dim3(tot/256), dim3(256), 0, stream,
                       qws, kws, cosT, sinT);
  }

  // attention: diagonal-paired blocks, 33 tiles each
  hipLaunchKernelGGL(attn_kernel, dim3(512), dim3(256), 0, stream,
                     qws, kws, vws, aows);

  // output projection, 256^2 8-phase -> fp32: 8x16 = 128 blocks
  hipLaunchKernelGGL(gemm256_kernel<0>, dim3(128), dim3(512), 131072, stream,
                     aows, wob, out, (ushort*)nullptr, (ushort*)nullptr, (ushort*)nullptr);
}